// Round 6
// baseline (781.300 us; speedup 1.0000x reference)
//
#include <hip/hip_runtime.h>
#include <hip/hip_bf16.h>
#include <math.h>

// ---------------------------------------------------------------------------
// GATEdgeNet. fp32 compute; gathered tensors (h1, h2, P) stored bf16.
//   1. CSR build grouped by dst (hist / hierarchical scan / scatter)
//      + edge sort by src row r (same scan machinery) for the edge MLP
//   2. h1b = bf16(x @ W_g1); as1/ad1 fused in GEMM epilogue (fp32-exact)
//   3. f1 = relu(agg(h1b) + b_g1)   -- no max pass (exp(e) safe, ratio exact)
//   4. h2b = bf16(f1 @ W_g2); as2/ad2 fused
//   5. f2 = relu(agg(h2b) + b_g2)
//   6. Pb = bf16([x|f2] @ W_m1[0:256])   (one dispatch, k-split A source)
//   7. edge MLP over r-sorted edges: P1[r] rows become L1/L2-local
// ---------------------------------------------------------------------------

#define GIN 64
#define GHID 128
#define GOUT 64

typedef unsigned int u32;
typedef unsigned short u16;

__device__ __forceinline__ float bflo(u32 u) {
  union { u32 i; float f; } c; c.i = u << 16; return c.f;
}
__device__ __forceinline__ float bfhi(u32 u) {
  union { u32 i; float f; } c; c.i = u & 0xffff0000u; return c.f;
}
__device__ __forceinline__ u16 f2bf(float x) {
  __hip_bfloat16 h = __float2bfloat16(x);
  return *reinterpret_cast<u16*>(&h);
}

// ---------------- CSR build (dst-grouped, 2E+N directed) -------------------

__global__ void hist_kernel(const int* __restrict__ eidx, int* __restrict__ deg,
                            int nE, int n) {
  int tot = 2 * nE + n;
  for (int i = blockIdx.x * blockDim.x + threadIdx.x; i < tot;
       i += gridDim.x * blockDim.x) {
    int dst;
    if (i < nE) dst = eidx[2 * i + 1];
    else if (i < 2 * nE) dst = eidx[2 * (i - nE)];
    else dst = i - 2 * nE;
    atomicAdd(&deg[dst], 1);
  }
}

// histogram of original-edge rows r (for the edge-MLP sort)
__global__ void hist_r(const int* __restrict__ eidx, int* __restrict__ deg2,
                       int nE) {
  for (int e = blockIdx.x * blockDim.x + threadIdx.x; e < nE;
       e += gridDim.x * blockDim.x) {
    atomicAdd(&deg2[eidx[2 * e]], 1);
  }
}

#define SCAN_CHUNK 1024
__global__ void scan_partial(const int* __restrict__ deg, int* __restrict__ bsum,
                             int n) {
  int b = blockIdx.x, tid = threadIdx.x;  // 256 threads
  int base = b * SCAN_CHUNK + tid * 4;
  int s = 0;
#pragma unroll
  for (int c = 0; c < 4; ++c) { int i = base + c; if (i < n) s += deg[i]; }
#pragma unroll
  for (int off = 32; off; off >>= 1) s += __shfl_xor(s, off, 64);
  __shared__ int ws[4];
  if ((tid & 63) == 0) ws[tid >> 6] = s;
  __syncthreads();
  if (tid == 0) bsum[b] = ws[0] + ws[1] + ws[2] + ws[3];
}
__global__ void scan_bsums(const int* __restrict__ bsum, int* __restrict__ bscan,
                           int* __restrict__ offs, int nb, int n) {
  int lane = threadIdx.x;
  int v = (lane < nb) ? bsum[lane] : 0;
  int incl = v;
#pragma unroll
  for (int off = 1; off < 64; off <<= 1) {
    int t = __shfl_up(incl, off, 64);
    if (lane >= off) incl += t;
  }
  if (lane < nb) bscan[lane] = incl - v;
  if (lane == 63) offs[n] = incl;
}
__global__ void scan_final(const int* __restrict__ deg, const int* __restrict__ bscan,
                           int* __restrict__ offs, int* __restrict__ cursor, int n) {
  int b = blockIdx.x, tid = threadIdx.x;
  int base = b * SCAN_CHUNK + tid * 4;
  int v[4]; int s = 0;
#pragma unroll
  for (int c = 0; c < 4; ++c) { int i = base + c; v[c] = (i < n) ? deg[i] : 0; s += v[c]; }
  int lane = tid & 63, wv = tid >> 6;
  int incl = s;
#pragma unroll
  for (int off = 1; off < 64; off <<= 1) {
    int t = __shfl_up(incl, off, 64);
    if (lane >= off) incl += t;
  }
  __shared__ int ws[4];
  if (lane == 63) ws[wv] = incl;
  __syncthreads();
  int woff = 0;
  for (int w2 = 0; w2 < wv; ++w2) woff += ws[w2];
  int excl = bscan[b] + woff + incl - s;
#pragma unroll
  for (int c = 0; c < 4; ++c) {
    int i = base + c;
    if (i < n) { offs[i] = excl; cursor[i] = excl; }
    excl += v[c];
  }
}

__global__ void scatter_kernel(const int* __restrict__ eidx, int* __restrict__ cursor,
                               int* __restrict__ csr, int nE, int n) {
  int tot = 2 * nE + n;
  for (int i = blockIdx.x * blockDim.x + threadIdx.x; i < tot;
       i += gridDim.x * blockDim.x) {
    int src, dst;
    if (i < nE)          { src = eidx[2 * i];            dst = eidx[2 * i + 1]; }
    else if (i < 2 * nE) { src = eidx[2 * (i - nE) + 1]; dst = eidx[2 * (i - nE)]; }
    else                 { src = i - 2 * nE;             dst = src; }
    int pos = atomicAdd(&cursor[dst], 1);
    csr[pos] = src;
  }
}

// scatter original edges into r-sorted order: ra[pos]=r, ce[pos]={c,e}
__global__ void scatter_r(const int* __restrict__ eidx, int* __restrict__ cur2,
                          int* __restrict__ ra, int2* __restrict__ ce, int nE) {
  for (int e = blockIdx.x * blockDim.x + threadIdx.x; e < nE;
       e += gridDim.x * blockDim.x) {
    int r = eidx[2 * e], c = eidx[2 * e + 1];
    int pos = atomicAdd(&cur2[r], 1);
    ra[pos] = r;
    ce[pos] = make_int2(c, e);
  }
}

// ---- fp32 GEMM, bf16 store, optional fused score dots, k-split A source ----

template <bool SCORES>
__global__ __launch_bounds__(256) void gemm_bf(
    const float* __restrict__ A, const float* __restrict__ A2, int ksp,
    int lda, int lda2,
    const float* __restrict__ B, int bskip, int ldb,
    u16* __restrict__ Cb, int ldcb,
    const float* __restrict__ av, const float* __restrict__ bv,
    float* __restrict__ as_, float* __restrict__ ad_,
    int M, int K) {
  __shared__ float As[32][68];   // 68 floats: rows 16B-aligned (17*16B)
  __shared__ float Bs[32][64];
  int tid = threadIdx.x;
  int m0 = blockIdx.x * 64;
  int n0 = blockIdx.y * 64;
  const float* Bp = B + (size_t)(n0 >> 7) * bskip;  // W_m1 row-chunk select
  int nb0 = n0 & 127;
  int tx = tid & 15, ty = tid >> 4;
  float acc[4][4] = {};
  for (int k0 = 0; k0 < K; k0 += 32) {
    const float* Asrc; int Alda; int kk;
    if (k0 < ksp) { Asrc = A;  Alda = lda;  kk = k0; }
    else          { Asrc = A2; Alda = lda2; kk = k0 - ksp; }
#pragma unroll
    for (int r = 0; r < 2; ++r) {   // A tile 64x32
      int m = (tid >> 3) + r * 32;
      int k = (tid & 7) * 4;
      float4 v = make_float4(0.f, 0.f, 0.f, 0.f);
      int gm = m0 + m;
      if (gm < M) v = *reinterpret_cast<const float4*>(&Asrc[(size_t)gm * Alda + kk + k]);
      As[k + 0][m] = v.x; As[k + 1][m] = v.y; As[k + 2][m] = v.z; As[k + 3][m] = v.w;
    }
#pragma unroll
    for (int r = 0; r < 2; ++r) {   // B tile 32x64
      int k = (tid >> 4) + r * 16;
      int nn = (tid & 15) * 4;
      float4 v = *reinterpret_cast<const float4*>(&Bp[(size_t)(k0 + k) * ldb + nb0 + nn]);
      *reinterpret_cast<float4*>(&Bs[k][nn]) = v;
    }
    __syncthreads();
#pragma unroll
    for (int k = 0; k < 32; ++k) {
      float a[4], b[4];
#pragma unroll
      for (int i = 0; i < 4; ++i) a[i] = As[k][ty * 4 + i];
#pragma unroll
      for (int i = 0; i < 4; ++i) b[i] = Bs[k][tx * 4 + i];
#pragma unroll
      for (int i = 0; i < 4; ++i)
#pragma unroll
        for (int j = 0; j < 4; ++j) acc[i][j] += a[i] * b[j];
    }
    __syncthreads();
  }
  float avv[4], bvv[4];
  if constexpr (SCORES) {
#pragma unroll
    for (int j = 0; j < 4; ++j) {
      avv[j] = av[n0 + tx * 4 + j];
      bvv[j] = bv[n0 + tx * 4 + j];
    }
  }
#pragma unroll
  for (int i = 0; i < 4; ++i) {
    int gm = m0 + ty * 4 + i;
    bool inb = gm < M;
    if (inb) {
      u16* bp = &Cb[(size_t)gm * ldcb + n0 + tx * 4];
      *reinterpret_cast<ushort4*>(bp) = make_ushort4(
          f2bf(acc[i][0]), f2bf(acc[i][1]), f2bf(acc[i][2]), f2bf(acc[i][3]));
    }
    if constexpr (SCORES) {
      float ps = acc[i][0] * avv[0] + acc[i][1] * avv[1] +
                 acc[i][2] * avv[2] + acc[i][3] * avv[3];
      float pd = acc[i][0] * bvv[0] + acc[i][1] * bvv[1] +
                 acc[i][2] * bvv[2] + acc[i][3] * bvv[3];
#pragma unroll
      for (int off = 1; off < 16; off <<= 1) {
        ps += __shfl_xor(ps, off, 16);
        pd += __shfl_xor(pd, off, 16);
      }
      if (tx == 0 && inb) {
        atomicAdd(&as_[gm], ps);
        atomicAdd(&ad_[gm], pd);
      }
    }
  }
}

// ---- GAT agg, D=128: no max pass, 4 nodes/block, 4 edges in flight --------

__global__ __launch_bounds__(256) void gat_agg1(
    const u16* __restrict__ hb, const float* __restrict__ as_,
    const float* __restrict__ ad_, const int* __restrict__ offs,
    const int* __restrict__ csr, const float* __restrict__ bias,
    float* __restrict__ out, int n) {
  int node = blockIdx.x * 4 + (threadIdx.x >> 6);
  if (node >= n) return;
  int lane = threadIdx.x & 63;
  int g = lane >> 4, sl = lane & 15;   // 4 edge slots, 8 cols per lane
  int beg = offs[node], end = offs[node + 1];
  float adn = ad_[node];
  float denom = 0.f;
  float a[8] = {};
  int i = beg + g;
  int s = (i < end) ? csr[i] : -1;
  uint4 pv = make_uint4(0, 0, 0, 0); float e = 0.f;
  if (s >= 0) {
    pv = *reinterpret_cast<const uint4*>(&hb[(size_t)s * 128 + sl * 8]);
    e = as_[s] + adn;
  }
  while (s >= 0) {
    int i2 = i + 4;
    int s2 = (i2 < end) ? csr[i2] : -1;
    uint4 pv2 = make_uint4(0, 0, 0, 0); float e2 = 0.f;
    if (s2 >= 0) {
      pv2 = *reinterpret_cast<const uint4*>(&hb[(size_t)s2 * 128 + sl * 8]);
      e2 = as_[s2] + adn;
    }
    e = (e > 0.f) ? e : 0.2f * e;
    float wgt = __expf(e);          // no max shift: e bounded ~|8|, safe
    denom += wgt;
    a[0] += wgt * bflo(pv.x); a[1] += wgt * bfhi(pv.x);
    a[2] += wgt * bflo(pv.y); a[3] += wgt * bfhi(pv.y);
    a[4] += wgt * bflo(pv.z); a[5] += wgt * bfhi(pv.z);
    a[6] += wgt * bflo(pv.w); a[7] += wgt * bfhi(pv.w);
    i = i2; s = s2; pv = pv2; e = e2;
  }
  denom += __shfl_xor(denom, 16, 64);
  denom += __shfl_xor(denom, 32, 64);
#pragma unroll
  for (int j = 0; j < 8; ++j) {
    a[j] += __shfl_xor(a[j], 16, 64);
    a[j] += __shfl_xor(a[j], 32, 64);
  }
  if (g == 0) {
    float inv = 1.f / (denom + 1e-16f);
    float4 b0 = *reinterpret_cast<const float4*>(&bias[sl * 8]);
    float4 b1v = *reinterpret_cast<const float4*>(&bias[sl * 8 + 4]);
    float4 o0, o1;
    o0.x = fmaxf(a[0] * inv + b0.x, 0.f);
    o0.y = fmaxf(a[1] * inv + b0.y, 0.f);
    o0.z = fmaxf(a[2] * inv + b0.z, 0.f);
    o0.w = fmaxf(a[3] * inv + b0.w, 0.f);
    o1.x = fmaxf(a[4] * inv + b1v.x, 0.f);
    o1.y = fmaxf(a[5] * inv + b1v.y, 0.f);
    o1.z = fmaxf(a[6] * inv + b1v.z, 0.f);
    o1.w = fmaxf(a[7] * inv + b1v.w, 0.f);
    *reinterpret_cast<float4*>(&out[(size_t)node * 128 + sl * 8]) = o0;
    *reinterpret_cast<float4*>(&out[(size_t)node * 128 + sl * 8 + 4]) = o1;
  }
}

// ---- GAT agg, D=64: no max pass, 4 nodes/block, 8 edges in flight ---------

__global__ __launch_bounds__(256) void gat_agg2(
    const u16* __restrict__ hb, const float* __restrict__ as_,
    const float* __restrict__ ad_, const int* __restrict__ offs,
    const int* __restrict__ csr, const float* __restrict__ bias,
    float* __restrict__ out, int n) {
  int node = blockIdx.x * 4 + (threadIdx.x >> 6);
  if (node >= n) return;
  int lane = threadIdx.x & 63;
  int g = lane >> 3, sl = lane & 7;   // 8 edge slots, 8 cols per lane
  int beg = offs[node], end = offs[node + 1];
  float adn = ad_[node];
  float denom = 0.f;
  float a[8] = {};
  int i = beg + g;
  int s = (i < end) ? csr[i] : -1;
  uint4 pv = make_uint4(0, 0, 0, 0); float e = 0.f;
  if (s >= 0) {
    pv = *reinterpret_cast<const uint4*>(&hb[(size_t)s * 64 + sl * 8]);
    e = as_[s] + adn;
  }
  while (s >= 0) {
    int i2 = i + 8;
    int s2 = (i2 < end) ? csr[i2] : -1;
    uint4 pv2 = make_uint4(0, 0, 0, 0); float e2 = 0.f;
    if (s2 >= 0) {
      pv2 = *reinterpret_cast<const uint4*>(&hb[(size_t)s2 * 64 + sl * 8]);
      e2 = as_[s2] + adn;
    }
    e = (e > 0.f) ? e : 0.2f * e;
    float wgt = __expf(e);
    denom += wgt;
    a[0] += wgt * bflo(pv.x); a[1] += wgt * bfhi(pv.x);
    a[2] += wgt * bflo(pv.y); a[3] += wgt * bfhi(pv.y);
    a[4] += wgt * bflo(pv.z); a[5] += wgt * bfhi(pv.z);
    a[6] += wgt * bflo(pv.w); a[7] += wgt * bfhi(pv.w);
    i = i2; s = s2; pv = pv2; e = e2;
  }
  denom += __shfl_xor(denom, 8, 64);
  denom += __shfl_xor(denom, 16, 64);
  denom += __shfl_xor(denom, 32, 64);
#pragma unroll
  for (int j = 0; j < 8; ++j) {
    a[j] += __shfl_xor(a[j], 8, 64);
    a[j] += __shfl_xor(a[j], 16, 64);
    a[j] += __shfl_xor(a[j], 32, 64);
  }
  if (g == 0) {
    float inv = 1.f / (denom + 1e-16f);
    float4 b0 = *reinterpret_cast<const float4*>(&bias[sl * 8]);
    float4 b1v = *reinterpret_cast<const float4*>(&bias[sl * 8 + 4]);
    float4 o0, o1;
    o0.x = fmaxf(a[0] * inv + b0.x, 0.f);
    o0.y = fmaxf(a[1] * inv + b0.y, 0.f);
    o0.z = fmaxf(a[2] * inv + b0.z, 0.f);
    o0.w = fmaxf(a[3] * inv + b0.w, 0.f);
    o1.x = fmaxf(a[4] * inv + b1v.x, 0.f);
    o1.y = fmaxf(a[5] * inv + b1v.y, 0.f);
    o1.z = fmaxf(a[6] * inv + b1v.z, 0.f);
    o1.w = fmaxf(a[7] * inv + b1v.w, 0.f);
    *reinterpret_cast<float4*>(&out[(size_t)node * 64 + sl * 8]) = o0;
    *reinterpret_cast<float4*>(&out[(size_t)node * 64 + sl * 8 + 4]) = o1;
  }
}

// ---- fused edge MLP over r-sorted edges: 4 edges/wave, 16 lanes/edge ------

__global__ __launch_bounds__(256) void edge_mlp(
    const int* __restrict__ ra, const int2* __restrict__ ce,
    const float* __restrict__ dist,
    const u16* __restrict__ Pb, const float* __restrict__ W3,
    const float* __restrict__ b1, const float* __restrict__ W2,
    const float* __restrict__ b2, float* __restrict__ out, int nE) {
  __shared__ float4 W3s[16][32];  // [k][q]: cols q*4..q*4+3
  int tid = threadIdx.x;
  for (int idx = tid; idx < 16 * 32; idx += 256) {
    int k = idx >> 5, q = idx & 31;
    W3s[k][q] = *reinterpret_cast<const float4*>(&W3[k * 128 + q * 4]);
  }
  __syncthreads();
  int lane = tid & 63, wv = tid >> 6;
  int g = lane >> 4, sl = lane & 15;   // edge slot g, 8 cols per lane
  float4 b1a = *reinterpret_cast<const float4*>(&b1[sl * 8]);
  float4 b1b = *reinterpret_cast<const float4*>(&b1[sl * 8 + 4]);
  float4 w2a = *reinterpret_cast<const float4*>(&W2[sl * 8]);
  float4 w2b = *reinterpret_cast<const float4*>(&W2[sl * 8 + 4]);
  float b2v = b2[0];
  for (int p0 = (blockIdx.x * 4 + wv) * 4; p0 < nE; p0 += gridDim.x * 16) {
    int p = p0 + g;
    bool valid = p < nE;
    int pp = valid ? p : 0;
    int r = ra[pp];
    int2 cece = ce[pp];
    int c = cece.x, e = cece.y;
    uint4 p1 = *reinterpret_cast<const uint4*>(&Pb[(size_t)r * 256 + sl * 8]);
    uint4 p2 = *reinterpret_cast<const uint4*>(&Pb[(size_t)c * 256 + 128 + sl * 8]);
    float dsl = dist[(size_t)e * 16 + sl];
    float a[8];
    a[0] = bflo(p1.x) + bflo(p2.x) + b1a.x;
    a[1] = bfhi(p1.x) + bfhi(p2.x) + b1a.y;
    a[2] = bflo(p1.y) + bflo(p2.y) + b1a.z;
    a[3] = bfhi(p1.y) + bfhi(p2.y) + b1a.w;
    a[4] = bflo(p1.z) + bflo(p2.z) + b1b.x;
    a[5] = bfhi(p1.z) + bfhi(p2.z) + b1b.y;
    a[6] = bflo(p1.w) + bflo(p2.w) + b1b.z;
    a[7] = bfhi(p1.w) + bfhi(p2.w) + b1b.w;
#pragma unroll
    for (int k = 0; k < 16; ++k) {
      float dk = __shfl(dsl, (g << 4) + k, 64);
      float4 wA = W3s[k][2 * sl];
      float4 wB = W3s[k][2 * sl + 1];
      a[0] += dk * wA.x; a[1] += dk * wA.y; a[2] += dk * wA.z; a[3] += dk * wA.w;
      a[4] += dk * wB.x; a[5] += dk * wB.y; a[6] += dk * wB.z; a[7] += dk * wB.w;
    }
    float p_ = fmaxf(a[0], 0.f) * w2a.x + fmaxf(a[1], 0.f) * w2a.y +
               fmaxf(a[2], 0.f) * w2a.z + fmaxf(a[3], 0.f) * w2a.w +
               fmaxf(a[4], 0.f) * w2b.x + fmaxf(a[5], 0.f) * w2b.y +
               fmaxf(a[6], 0.f) * w2b.z + fmaxf(a[7], 0.f) * w2b.w;
#pragma unroll
    for (int off = 1; off < 16; off <<= 1) p_ += __shfl_xor(p_, off, 16);
    if (valid && sl == 0) out[e] = 1.f / (1.f + __expf(-(p_ + b2v)));
  }
}

// ---------------- launch ---------------------------------------------------

extern "C" void kernel_launch(void* const* d_in, const int* in_sizes, int n_in,
                              void* d_out, int out_size, void* d_ws, size_t ws_size,
                              hipStream_t stream) {
  const float* x      = (const float*)d_in[0];
  const int*   eidx   = (const int*)d_in[1];
  const float* dist   = (const float*)d_in[2];
  const float* W_g1   = (const float*)d_in[3];
  const float* a1_src = (const float*)d_in[4];
  const float* a1_dst = (const float*)d_in[5];
  const float* b_g1   = (const float*)d_in[6];
  const float* W_g2   = (const float*)d_in[7];
  const float* a2_src = (const float*)d_in[8];
  const float* a2_dst = (const float*)d_in[9];
  const float* b_g2   = (const float*)d_in[10];
  const float* W_m1   = (const float*)d_in[11];
  const float* b_m1   = (const float*)d_in[12];
  const float* W_m2   = (const float*)d_in[13];
  const float* b_m2   = (const float*)d_in[14];
  float* out = (float*)d_out;

  const int n  = in_sizes[0] / GIN;   // 50000
  const int nE = in_sizes[1] / 2;     // 800000
  const int ndir = 2 * nE + n;        // 1,650,000

  char* w = (char*)d_ws;
  size_t off = 0;
  auto alloc = [&](size_t bytes) {
    size_t o = off;
    off += (bytes + 255) & ~(size_t)255;
    return o;
  };
  size_t o_deg    = alloc((size_t)n * 4);
  size_t o_offs   = alloc((size_t)(n + 1) * 4);
  size_t o_cursor = alloc((size_t)n * 4);
  size_t o_deg2   = alloc((size_t)n * 4);
  size_t o_offs2  = alloc((size_t)(n + 1) * 4);
  size_t o_as1    = alloc((size_t)n * 4);
  size_t o_ad1    = alloc((size_t)n * 4);
  size_t o_as2    = alloc((size_t)n * 4);
  size_t o_ad2    = alloc((size_t)n * 4);
  size_t o_bsum   = alloc(64 * 4);
  size_t o_bscan  = alloc(64 * 4);
  size_t o_csr    = alloc((size_t)ndir * 4);
  size_t o_ra     = alloc((size_t)nE * 4);
  size_t o_ce     = alloc((size_t)nE * 8);
  size_t o_big    = alloc((size_t)n * 256 * 2);  // Pb; h1b/h2b overlay
  size_t o_f1     = alloc((size_t)n * GHID * 4);
  size_t o_f2     = alloc((size_t)n * GOUT * 4);
  (void)ws_size;

  int*   deg    = (int*)(w + o_deg);
  int*   offs   = (int*)(w + o_offs);
  int*   cursor = (int*)(w + o_cursor);
  int*   deg2   = (int*)(w + o_deg2);
  int*   cur2   = (int*)(w + o_offs2);
  float* as1    = (float*)(w + o_as1);
  float* ad1    = (float*)(w + o_ad1);
  float* as2    = (float*)(w + o_as2);
  float* ad2    = (float*)(w + o_ad2);
  int*   bsum   = (int*)(w + o_bsum);
  int*   bscan  = (int*)(w + o_bscan);
  int*   csr    = (int*)(w + o_csr);
  int*   ra     = (int*)(w + o_ra);
  int2*  ce     = (int2*)(w + o_ce);
  u16*   h1b    = (u16*)(w + o_big);                          // dead after agg1
  u16*   h2b    = (u16*)(w + o_big + (size_t)n * GHID * 2);   // dead after agg2
  u16*   Pb     = (u16*)(w + o_big);                          // overlays h1b/h2b
  float* f1     = (float*)(w + o_f1);
  float* f2     = (float*)(w + o_f2);

  // 1. CSR build (dst-grouped) + r-sort of original edges + score zeroing
  hipMemsetAsync(deg, 0, (size_t)n * 4, stream);
  hipMemsetAsync(deg2, 0, (size_t)n * 4, stream);
  hipMemsetAsync(as1, 0, (size_t)n * 4, stream);
  hipMemsetAsync(ad1, 0, (size_t)n * 4, stream);
  hipMemsetAsync(as2, 0, (size_t)n * 4, stream);
  hipMemsetAsync(ad2, 0, (size_t)n * 4, stream);
  hist_kernel<<<2048, 256, 0, stream>>>(eidx, deg, nE, n);
  hist_r<<<1024, 256, 0, stream>>>(eidx, deg2, nE);
  int nb = (n + SCAN_CHUNK - 1) / SCAN_CHUNK;  // 49 (<=64 required)
  // dst-CSR scan
  scan_partial<<<nb, 256, 0, stream>>>(deg, bsum, n);
  scan_bsums<<<1, 64, 0, stream>>>(bsum, bscan, offs, nb, n);
  scan_final<<<nb, 256, 0, stream>>>(deg, bscan, offs, cursor, n);
  scatter_kernel<<<2048, 256, 0, stream>>>(eidx, cursor, csr, nE, n);
  // r-sort scan (cursor only; offs2 slot holds the cursor)
  scan_partial<<<nb, 256, 0, stream>>>(deg2, bsum, n);
  scan_bsums<<<1, 64, 0, stream>>>(bsum, bscan, (int*)(w + o_offs2), nb, n);
  scan_final<<<nb, 256, 0, stream>>>(deg2, bscan, deg2 /*offs out, reuse*/, cur2, n);
  scatter_r<<<1024, 256, 0, stream>>>(eidx, cur2, ra, ce, nE);

  const int mtiles = (n + 63) / 64;  // 782
  const int BIGK = 1 << 30;

  // 2. h1b = bf16(x @ W_g1), as1/ad1 fused
  gemm_bf<true><<<dim3(mtiles, 2), 256, 0, stream>>>(
      x, x, BIGK, GIN, GIN, W_g1, 0, GHID, h1b, GHID,
      a1_src, a1_dst, as1, ad1, n, GIN);

  // 3. f1 = relu(agg(h1b) + b_g1)
  gat_agg1<<<(n + 3) / 4, 256, 0, stream>>>(h1b, as1, ad1, offs, csr, b_g1, f1, n);

  // 4. h2b = bf16(f1 @ W_g2), as2/ad2 fused
  gemm_bf<true><<<dim3(mtiles, 1), 256, 0, stream>>>(
      f1, f1, BIGK, GHID, GHID, W_g2, 0, GOUT, h2b, GOUT,
      a2_src, a2_dst, as2, ad2, n, GHID);

  // 5. f2 = relu(agg(h2b) + b_g2)
  gat_agg2<<<(n + 3) / 4, 256, 0, stream>>>(h2b, as2, ad2, offs, csr, b_g2, f2, n);

  // 6. Pb = bf16([x|f2] @ W_m1[0:256]) — one dispatch, k-split A, B row-chunk
  gemm_bf<false><<<dim3(mtiles, 4), 256, 0, stream>>>(
      x, f2, GIN, GIN, GOUT, W_m1, 128 * 128, GHID, Pb, 256,
      nullptr, nullptr, nullptr, nullptr, n, GHID);

  // 7. fused edge MLP + sigmoid over r-sorted edges
  edge_mlp<<<4096, 256, 0, stream>>>(ra, ce, dist, Pb, W_m1 + 256 * 128, b_m1,
                                     W_m2, b_m2, out, nE);
}

// Round 7
// 651.477 us; speedup vs baseline: 1.1993x; 1.1993x over previous
//
#include <hip/hip_runtime.h>
#include <hip/hip_bf16.h>
#include <math.h>

// ---------------------------------------------------------------------------
// GATEdgeNet. fp32 compute; gathered tensors (h1, h2, P) stored bf16.
// Gather kernels are latency-bound (random 128-256B row gathers): all three
// use deep software pipelines (index loads 2 ahead, row loads 1 ahead) and
// many edge slots per wave to maximize outstanding requests.
//   1. CSR build grouped by dst (hist / hierarchical scan / scatter)
//   2. h1b = bf16(x @ W_g1); as1/ad1 fused in GEMM epilogue (fp32-exact)
//   3. f1 = relu(agg(h1b) + b_g1)   -- no max pass (exp(e) bounded, ratio exact)
//   4. h2b = bf16(f1 @ W_g2); as2/ad2 fused
//   5. f2 = relu(agg(h2b) + b_g2)
//   6. Pb = bf16([x|f2] @ W_m1[0:256])   (one dispatch, k-split A source)
//   7. edge MLP in original edge order (streamed eidx/dist/out, random P)
// ---------------------------------------------------------------------------

#define GIN 64
#define GHID 128
#define GOUT 64

typedef unsigned int u32;
typedef unsigned short u16;

__device__ __forceinline__ float bflo(u32 u) {
  union { u32 i; float f; } c; c.i = u << 16; return c.f;
}
__device__ __forceinline__ float bfhi(u32 u) {
  union { u32 i; float f; } c; c.i = u & 0xffff0000u; return c.f;
}
__device__ __forceinline__ u16 f2bf(float x) {
  __hip_bfloat16 h = __float2bfloat16(x);
  return *reinterpret_cast<u16*>(&h);
}

// ---------------- CSR build (dst-grouped, 2E+N directed) -------------------

__global__ void hist_kernel(const int* __restrict__ eidx, int* __restrict__ deg,
                            int nE, int n) {
  int tot = 2 * nE + n;
  for (int i = blockIdx.x * blockDim.x + threadIdx.x; i < tot;
       i += gridDim.x * blockDim.x) {
    int dst;
    if (i < nE) dst = eidx[2 * i + 1];
    else if (i < 2 * nE) dst = eidx[2 * (i - nE)];
    else dst = i - 2 * nE;
    atomicAdd(&deg[dst], 1);
  }
}

#define SCAN_CHUNK 1024
__global__ void scan_partial(const int* __restrict__ deg, int* __restrict__ bsum,
                             int n) {
  int b = blockIdx.x, tid = threadIdx.x;  // 256 threads
  int base = b * SCAN_CHUNK + tid * 4;
  int s = 0;
#pragma unroll
  for (int c = 0; c < 4; ++c) { int i = base + c; if (i < n) s += deg[i]; }
#pragma unroll
  for (int off = 32; off; off >>= 1) s += __shfl_xor(s, off, 64);
  __shared__ int ws[4];
  if ((tid & 63) == 0) ws[tid >> 6] = s;
  __syncthreads();
  if (tid == 0) bsum[b] = ws[0] + ws[1] + ws[2] + ws[3];
}
__global__ void scan_bsums(const int* __restrict__ bsum, int* __restrict__ bscan,
                           int* __restrict__ offs, int nb, int n) {
  int lane = threadIdx.x;
  int v = (lane < nb) ? bsum[lane] : 0;
  int incl = v;
#pragma unroll
  for (int off = 1; off < 64; off <<= 1) {
    int t = __shfl_up(incl, off, 64);
    if (lane >= off) incl += t;
  }
  if (lane < nb) bscan[lane] = incl - v;
  if (lane == 63) offs[n] = incl;
}
__global__ void scan_final(const int* __restrict__ deg, const int* __restrict__ bscan,
                           int* __restrict__ offs, int* __restrict__ cursor, int n) {
  int b = blockIdx.x, tid = threadIdx.x;
  int base = b * SCAN_CHUNK + tid * 4;
  int v[4]; int s = 0;
#pragma unroll
  for (int c = 0; c < 4; ++c) { int i = base + c; v[c] = (i < n) ? deg[i] : 0; s += v[c]; }
  int lane = tid & 63, wv = tid >> 6;
  int incl = s;
#pragma unroll
  for (int off = 1; off < 64; off <<= 1) {
    int t = __shfl_up(incl, off, 64);
    if (lane >= off) incl += t;
  }
  __shared__ int ws[4];
  if (lane == 63) ws[wv] = incl;
  __syncthreads();
  int woff = 0;
  for (int w2 = 0; w2 < wv; ++w2) woff += ws[w2];
  int excl = bscan[b] + woff + incl - s;
#pragma unroll
  for (int c = 0; c < 4; ++c) {
    int i = base + c;
    if (i < n) { offs[i] = excl; cursor[i] = excl; }
    excl += v[c];
  }
}

__global__ void scatter_kernel(const int* __restrict__ eidx, int* __restrict__ cursor,
                               int* __restrict__ csr, int nE, int n) {
  int tot = 2 * nE + n;
  for (int i = blockIdx.x * blockDim.x + threadIdx.x; i < tot;
       i += gridDim.x * blockDim.x) {
    int src, dst;
    if (i < nE)          { src = eidx[2 * i];            dst = eidx[2 * i + 1]; }
    else if (i < 2 * nE) { src = eidx[2 * (i - nE) + 1]; dst = eidx[2 * (i - nE)]; }
    else                 { src = i - 2 * nE;             dst = src; }
    int pos = atomicAdd(&cursor[dst], 1);
    csr[pos] = src;
  }
}

// ---- fp32 GEMM, bf16 store, optional fused score dots, k-split A source ----

template <bool SCORES>
__global__ __launch_bounds__(256) void gemm_bf(
    const float* __restrict__ A, const float* __restrict__ A2, int ksp,
    int lda, int lda2,
    const float* __restrict__ B, int bskip, int ldb,
    u16* __restrict__ Cb, int ldcb,
    const float* __restrict__ av, const float* __restrict__ bv,
    float* __restrict__ as_, float* __restrict__ ad_,
    int M, int K) {
  __shared__ float As[32][68];   // 68 floats: rows 16B-aligned (17*16B)
  __shared__ float Bs[32][64];
  int tid = threadIdx.x;
  int m0 = blockIdx.x * 64;
  int n0 = blockIdx.y * 64;
  const float* Bp = B + (size_t)(n0 >> 7) * bskip;  // W_m1 row-chunk select
  int nb0 = n0 & 127;
  int tx = tid & 15, ty = tid >> 4;
  float acc[4][4] = {};
  for (int k0 = 0; k0 < K; k0 += 32) {
    const float* Asrc; int Alda; int kk;
    if (k0 < ksp) { Asrc = A;  Alda = lda;  kk = k0; }
    else          { Asrc = A2; Alda = lda2; kk = k0 - ksp; }
#pragma unroll
    for (int r = 0; r < 2; ++r) {   // A tile 64x32
      int m = (tid >> 3) + r * 32;
      int k = (tid & 7) * 4;
      float4 v = make_float4(0.f, 0.f, 0.f, 0.f);
      int gm = m0 + m;
      if (gm < M) v = *reinterpret_cast<const float4*>(&Asrc[(size_t)gm * Alda + kk + k]);
      As[k + 0][m] = v.x; As[k + 1][m] = v.y; As[k + 2][m] = v.z; As[k + 3][m] = v.w;
    }
#pragma unroll
    for (int r = 0; r < 2; ++r) {   // B tile 32x64
      int k = (tid >> 4) + r * 16;
      int nn = (tid & 15) * 4;
      float4 v = *reinterpret_cast<const float4*>(&Bp[(size_t)(k0 + k) * ldb + nb0 + nn]);
      *reinterpret_cast<float4*>(&Bs[k][nn]) = v;
    }
    __syncthreads();
#pragma unroll
    for (int k = 0; k < 32; ++k) {
      float a[4], b[4];
#pragma unroll
      for (int i = 0; i < 4; ++i) a[i] = As[k][ty * 4 + i];
#pragma unroll
      for (int i = 0; i < 4; ++i) b[i] = Bs[k][tx * 4 + i];
#pragma unroll
      for (int i = 0; i < 4; ++i)
#pragma unroll
        for (int j = 0; j < 4; ++j) acc[i][j] += a[i] * b[j];
    }
    __syncthreads();
  }
  float avv[4], bvv[4];
  if constexpr (SCORES) {
#pragma unroll
    for (int j = 0; j < 4; ++j) {
      avv[j] = av[n0 + tx * 4 + j];
      bvv[j] = bv[n0 + tx * 4 + j];
    }
  }
#pragma unroll
  for (int i = 0; i < 4; ++i) {
    int gm = m0 + ty * 4 + i;
    bool inb = gm < M;
    if (inb) {
      u16* bp = &Cb[(size_t)gm * ldcb + n0 + tx * 4];
      *reinterpret_cast<ushort4*>(bp) = make_ushort4(
          f2bf(acc[i][0]), f2bf(acc[i][1]), f2bf(acc[i][2]), f2bf(acc[i][3]));
    }
    if constexpr (SCORES) {
      float ps = acc[i][0] * avv[0] + acc[i][1] * avv[1] +
                 acc[i][2] * avv[2] + acc[i][3] * avv[3];
      float pd = acc[i][0] * bvv[0] + acc[i][1] * bvv[1] +
                 acc[i][2] * bvv[2] + acc[i][3] * bvv[3];
#pragma unroll
      for (int off = 1; off < 16; off <<= 1) {
        ps += __shfl_xor(ps, off, 16);
        pd += __shfl_xor(pd, off, 16);
      }
      if (tx == 0 && inb) {
        atomicAdd(&as_[gm], ps);
        atomicAdd(&ad_[gm], pd);
      }
    }
  }
}

// ---- GAT agg, D=128: 8 edge slots/wave (8 lanes/edge), 2-level pipeline ---

__global__ __launch_bounds__(256) void gat_agg1(
    const u16* __restrict__ hb, const float* __restrict__ as_,
    const float* __restrict__ ad_, const int* __restrict__ offs,
    const int* __restrict__ csr, const float* __restrict__ bias,
    float* __restrict__ out, int n) {
  int node = blockIdx.x * 4 + (threadIdx.x >> 6);
  if (node >= n) return;
  int lane = threadIdx.x & 63;
  int g = lane >> 3, sl = lane & 7;   // 8 slots, lane covers cols sl*16..+15
  int beg = offs[node], end = offs[node + 1];
  float adn = ad_[node];
  float denom = 0.f;
  float a[16] = {};
  // pipeline: s index 1 ahead (s1), data 0 (current in regs)
  int i0 = beg + g;
  int s0 = (i0 < end) ? csr[i0] : -1;
  uint4 pa0 = make_uint4(0,0,0,0), pb0 = make_uint4(0,0,0,0); float e0 = 0.f;
  if (s0 >= 0) {
    const u16* row = &hb[(size_t)s0 * 128 + sl * 16];
    pa0 = *reinterpret_cast<const uint4*>(row);
    pb0 = *reinterpret_cast<const uint4*>(row + 8);
    e0 = as_[s0] + adn;
  }
  int i1 = i0 + 8;
  int s1 = (i1 < end) ? csr[i1] : -1;
  while (s0 >= 0) {
    int i2 = i1 + 8;
    int s2 = (i2 < end) ? csr[i2] : -1;          // index 2 ahead
    uint4 pa1 = make_uint4(0,0,0,0), pb1 = make_uint4(0,0,0,0); float e1 = 0.f;
    if (s1 >= 0) {                               // data 1 ahead (addr resident)
      const u16* row = &hb[(size_t)s1 * 128 + sl * 16];
      pa1 = *reinterpret_cast<const uint4*>(row);
      pb1 = *reinterpret_cast<const uint4*>(row + 8);
      e1 = as_[s1] + adn;
    }
    // compute current
    float e = (e0 > 0.f) ? e0 : 0.2f * e0;
    float wgt = __expf(e);
    denom += wgt;
    a[0]  += wgt * bflo(pa0.x); a[1]  += wgt * bfhi(pa0.x);
    a[2]  += wgt * bflo(pa0.y); a[3]  += wgt * bfhi(pa0.y);
    a[4]  += wgt * bflo(pa0.z); a[5]  += wgt * bfhi(pa0.z);
    a[6]  += wgt * bflo(pa0.w); a[7]  += wgt * bfhi(pa0.w);
    a[8]  += wgt * bflo(pb0.x); a[9]  += wgt * bfhi(pb0.x);
    a[10] += wgt * bflo(pb0.y); a[11] += wgt * bfhi(pb0.y);
    a[12] += wgt * bflo(pb0.z); a[13] += wgt * bfhi(pb0.z);
    a[14] += wgt * bflo(pb0.w); a[15] += wgt * bfhi(pb0.w);
    s0 = s1; pa0 = pa1; pb0 = pb1; e0 = e1;
    s1 = s2; i1 = i2;
  }
  denom += __shfl_xor(denom, 8, 64);
  denom += __shfl_xor(denom, 16, 64);
  denom += __shfl_xor(denom, 32, 64);
#pragma unroll
  for (int j = 0; j < 16; ++j) {
    a[j] += __shfl_xor(a[j], 8, 64);
    a[j] += __shfl_xor(a[j], 16, 64);
    a[j] += __shfl_xor(a[j], 32, 64);
  }
  if (g == 0) {
    float inv = 1.f / (denom + 1e-16f);
    float* op = &out[(size_t)node * 128 + sl * 16];
    const float* bp = &bias[sl * 16];
#pragma unroll
    for (int q = 0; q < 4; ++q) {
      float4 bq = *reinterpret_cast<const float4*>(bp + q * 4);
      float4 o;
      o.x = fmaxf(a[q * 4 + 0] * inv + bq.x, 0.f);
      o.y = fmaxf(a[q * 4 + 1] * inv + bq.y, 0.f);
      o.z = fmaxf(a[q * 4 + 2] * inv + bq.z, 0.f);
      o.w = fmaxf(a[q * 4 + 3] * inv + bq.w, 0.f);
      *reinterpret_cast<float4*>(op + q * 4) = o;
    }
  }
}

// ---- GAT agg, D=64: 16 edge slots/wave (4 lanes/edge), 2-level pipeline ---

__global__ __launch_bounds__(256) void gat_agg2(
    const u16* __restrict__ hb, const float* __restrict__ as_,
    const float* __restrict__ ad_, const int* __restrict__ offs,
    const int* __restrict__ csr, const float* __restrict__ bias,
    float* __restrict__ out, int n) {
  int node = blockIdx.x * 4 + (threadIdx.x >> 6);
  if (node >= n) return;
  int lane = threadIdx.x & 63;
  int g = lane >> 2, sl = lane & 3;   // 16 slots, lane covers cols sl*16..+15
  int beg = offs[node], end = offs[node + 1];
  float adn = ad_[node];
  float denom = 0.f;
  float a[16] = {};
  int i0 = beg + g;
  int s0 = (i0 < end) ? csr[i0] : -1;
  uint4 pa0 = make_uint4(0,0,0,0), pb0 = make_uint4(0,0,0,0); float e0 = 0.f;
  if (s0 >= 0) {
    const u16* row = &hb[(size_t)s0 * 64 + sl * 16];
    pa0 = *reinterpret_cast<const uint4*>(row);
    pb0 = *reinterpret_cast<const uint4*>(row + 8);
    e0 = as_[s0] + adn;
  }
  int i1 = i0 + 16;
  int s1 = (i1 < end) ? csr[i1] : -1;
  while (s0 >= 0) {
    int i2 = i1 + 16;
    int s2 = (i2 < end) ? csr[i2] : -1;
    uint4 pa1 = make_uint4(0,0,0,0), pb1 = make_uint4(0,0,0,0); float e1 = 0.f;
    if (s1 >= 0) {
      const u16* row = &hb[(size_t)s1 * 64 + sl * 16];
      pa1 = *reinterpret_cast<const uint4*>(row);
      pb1 = *reinterpret_cast<const uint4*>(row + 8);
      e1 = as_[s1] + adn;
    }
    float e = (e0 > 0.f) ? e0 : 0.2f * e0;
    float wgt = __expf(e);
    denom += wgt;
    a[0]  += wgt * bflo(pa0.x); a[1]  += wgt * bfhi(pa0.x);
    a[2]  += wgt * bflo(pa0.y); a[3]  += wgt * bfhi(pa0.y);
    a[4]  += wgt * bflo(pa0.z); a[5]  += wgt * bfhi(pa0.z);
    a[6]  += wgt * bflo(pa0.w); a[7]  += wgt * bfhi(pa0.w);
    a[8]  += wgt * bflo(pb0.x); a[9]  += wgt * bfhi(pb0.x);
    a[10] += wgt * bflo(pb0.y); a[11] += wgt * bfhi(pb0.y);
    a[12] += wgt * bflo(pb0.z); a[13] += wgt * bfhi(pb0.z);
    a[14] += wgt * bflo(pb0.w); a[15] += wgt * bfhi(pb0.w);
    s0 = s1; pa0 = pa1; pb0 = pb1; e0 = e1;
    s1 = s2; i1 = i2;
  }
#pragma unroll
  for (int w2 = 4; w2 < 64; w2 <<= 1) denom += __shfl_xor(denom, w2, 64);
#pragma unroll
  for (int j = 0; j < 16; ++j) {
    a[j] += __shfl_xor(a[j], 4, 64);
    a[j] += __shfl_xor(a[j], 8, 64);
    a[j] += __shfl_xor(a[j], 16, 64);
    a[j] += __shfl_xor(a[j], 32, 64);
  }
  if (g == 0) {
    float inv = 1.f / (denom + 1e-16f);
    float* op = &out[(size_t)node * 64 + sl * 16];
    const float* bp = &bias[sl * 16];
#pragma unroll
    for (int q = 0; q < 4; ++q) {
      float4 bq = *reinterpret_cast<const float4*>(bp + q * 4);
      float4 o;
      o.x = fmaxf(a[q * 4 + 0] * inv + bq.x, 0.f);
      o.y = fmaxf(a[q * 4 + 1] * inv + bq.y, 0.f);
      o.z = fmaxf(a[q * 4 + 2] * inv + bq.z, 0.f);
      o.w = fmaxf(a[q * 4 + 3] * inv + bq.w, 0.f);
      *reinterpret_cast<float4*>(op + q * 4) = o;
    }
  }
}

// ---- fused edge MLP: original edge order, 4 edges/wave, 2-level pipeline --

__global__ __launch_bounds__(256) void edge_mlp(
    const int2* __restrict__ eidx, const float* __restrict__ dist,
    const u16* __restrict__ Pb, const float* __restrict__ W3,
    const float* __restrict__ b1, const float* __restrict__ W2,
    const float* __restrict__ b2, float* __restrict__ out, int nE) {
  __shared__ float4 W3s[16][32];  // [k][q]: cols q*4..q*4+3
  int tid = threadIdx.x;
  for (int idx = tid; idx < 16 * 32; idx += 256) {
    int k = idx >> 5, q = idx & 31;
    W3s[k][q] = *reinterpret_cast<const float4*>(&W3[k * 128 + q * 4]);
  }
  __syncthreads();
  int lane = tid & 63, wv = tid >> 6;
  int g = lane >> 4, sl = lane & 15;   // edge slot g, 8 cols per lane
  float4 b1a = *reinterpret_cast<const float4*>(&b1[sl * 8]);
  float4 b1b = *reinterpret_cast<const float4*>(&b1[sl * 8 + 4]);
  float4 w2a = *reinterpret_cast<const float4*>(&W2[sl * 8]);
  float4 w2b = *reinterpret_cast<const float4*>(&W2[sl * 8 + 4]);
  float b2v = b2[0];
  const int stride = gridDim.x * 16;
  // pipeline state: edge e0 (data resident), e1 (index resident)
  int e0 = (blockIdx.x * 4 + wv) * 4 + g;
  bool v0 = e0 < nE;
  int2 rc0 = v0 ? eidx[e0] : make_int2(0, 0);
  uint4 p1 = make_uint4(0,0,0,0), p2 = make_uint4(0,0,0,0); float ds0 = 0.f;
  if (v0) {
    p1 = *reinterpret_cast<const uint4*>(&Pb[(size_t)rc0.x * 256 + sl * 8]);
    p2 = *reinterpret_cast<const uint4*>(&Pb[(size_t)rc0.y * 256 + 128 + sl * 8]);
    ds0 = dist[(size_t)e0 * 16 + sl];
  }
  int e1 = e0 + stride;
  bool v1 = e1 < nE;
  int2 rc1 = v1 ? eidx[e1] : make_int2(0, 0);
  while (v0) {
    int e2 = e1 + stride;
    bool v2 = e2 < nE;
    int2 rc2 = v2 ? eidx[e2] : make_int2(0, 0);     // index 2 ahead
    uint4 q1 = make_uint4(0,0,0,0), q2 = make_uint4(0,0,0,0); float ds1 = 0.f;
    if (v1) {                                        // data 1 ahead
      q1 = *reinterpret_cast<const uint4*>(&Pb[(size_t)rc1.x * 256 + sl * 8]);
      q2 = *reinterpret_cast<const uint4*>(&Pb[(size_t)rc1.y * 256 + 128 + sl * 8]);
      ds1 = dist[(size_t)e1 * 16 + sl];
    }
    // compute current edge e0
    float a[8];
    a[0] = bflo(p1.x) + bflo(p2.x) + b1a.x;
    a[1] = bfhi(p1.x) + bfhi(p2.x) + b1a.y;
    a[2] = bflo(p1.y) + bflo(p2.y) + b1a.z;
    a[3] = bfhi(p1.y) + bfhi(p2.y) + b1a.w;
    a[4] = bflo(p1.z) + bflo(p2.z) + b1b.x;
    a[5] = bfhi(p1.z) + bfhi(p2.z) + b1b.y;
    a[6] = bflo(p1.w) + bflo(p2.w) + b1b.z;
    a[7] = bfhi(p1.w) + bfhi(p2.w) + b1b.w;
#pragma unroll
    for (int k = 0; k < 16; ++k) {
      float dk = __shfl(ds0, (g << 4) + k, 64);
      float4 wA = W3s[k][2 * sl];
      float4 wB = W3s[k][2 * sl + 1];
      a[0] += dk * wA.x; a[1] += dk * wA.y; a[2] += dk * wA.z; a[3] += dk * wA.w;
      a[4] += dk * wB.x; a[5] += dk * wB.y; a[6] += dk * wB.z; a[7] += dk * wB.w;
    }
    float p_ = fmaxf(a[0], 0.f) * w2a.x + fmaxf(a[1], 0.f) * w2a.y +
               fmaxf(a[2], 0.f) * w2a.z + fmaxf(a[3], 0.f) * w2a.w +
               fmaxf(a[4], 0.f) * w2b.x + fmaxf(a[5], 0.f) * w2b.y +
               fmaxf(a[6], 0.f) * w2b.z + fmaxf(a[7], 0.f) * w2b.w;
#pragma unroll
    for (int off = 1; off < 16; off <<= 1) p_ += __shfl_xor(p_, off, 16);
    if (sl == 0) out[e0] = 1.f / (1.f + __expf(-(p_ + b2v)));
    // rotate
    e0 = e1; v0 = v1; p1 = q1; p2 = q2; ds0 = ds1;
    e1 = e2; v1 = v2; rc1 = rc2;
  }
}

// ---------------- launch ---------------------------------------------------

extern "C" void kernel_launch(void* const* d_in, const int* in_sizes, int n_in,
                              void* d_out, int out_size, void* d_ws, size_t ws_size,
                              hipStream_t stream) {
  const float* x      = (const float*)d_in[0];
  const int*   eidx   = (const int*)d_in[1];
  const float* dist   = (const float*)d_in[2];
  const float* W_g1   = (const float*)d_in[3];
  const float* a1_src = (const float*)d_in[4];
  const float* a1_dst = (const float*)d_in[5];
  const float* b_g1   = (const float*)d_in[6];
  const float* W_g2   = (const float*)d_in[7];
  const float* a2_src = (const float*)d_in[8];
  const float* a2_dst = (const float*)d_in[9];
  const float* b_g2   = (const float*)d_in[10];
  const float* W_m1   = (const float*)d_in[11];
  const float* b_m1   = (const float*)d_in[12];
  const float* W_m2   = (const float*)d_in[13];
  const float* b_m2   = (const float*)d_in[14];
  float* out = (float*)d_out;

  const int n  = in_sizes[0] / GIN;   // 50000
  const int nE = in_sizes[1] / 2;     // 800000
  const int ndir = 2 * nE + n;        // 1,650,000

  char* w = (char*)d_ws;
  size_t off = 0;
  auto alloc = [&](size_t bytes) {
    size_t o = off;
    off += (bytes + 255) & ~(size_t)255;
    return o;
  };
  size_t o_deg    = alloc((size_t)n * 4);
  size_t o_offs   = alloc((size_t)(n + 1) * 4);
  size_t o_cursor = alloc((size_t)n * 4);
  size_t o_as1    = alloc((size_t)n * 4);
  size_t o_ad1    = alloc((size_t)n * 4);
  size_t o_as2    = alloc((size_t)n * 4);
  size_t o_ad2    = alloc((size_t)n * 4);
  size_t o_bsum   = alloc(64 * 4);
  size_t o_bscan  = alloc(64 * 4);
  size_t o_csr    = alloc((size_t)ndir * 4);
  size_t o_big    = alloc((size_t)n * 256 * 2);  // Pb; h1b/h2b overlay
  size_t o_f1     = alloc((size_t)n * GHID * 4);
  size_t o_f2     = alloc((size_t)n * GOUT * 4);
  (void)ws_size;

  int*   deg    = (int*)(w + o_deg);
  int*   offs   = (int*)(w + o_offs);
  int*   cursor = (int*)(w + o_cursor);
  float* as1    = (float*)(w + o_as1);
  float* ad1    = (float*)(w + o_ad1);
  float* as2    = (float*)(w + o_as2);
  float* ad2    = (float*)(w + o_ad2);
  int*   bsum   = (int*)(w + o_bsum);
  int*   bscan  = (int*)(w + o_bscan);
  int*   csr    = (int*)(w + o_csr);
  u16*   h1b    = (u16*)(w + o_big);                          // dead after agg1
  u16*   h2b    = (u16*)(w + o_big + (size_t)n * GHID * 2);   // dead after agg2
  u16*   Pb     = (u16*)(w + o_big);                          // overlays h1b/h2b
  float* f1     = (float*)(w + o_f1);
  float* f2     = (float*)(w + o_f2);

  // 1. CSR build (dst-grouped) + score-accumulator zeroing
  hipMemsetAsync(deg, 0, (size_t)n * 4, stream);
  hipMemsetAsync(as1, 0, (size_t)n * 4, stream);
  hipMemsetAsync(ad1, 0, (size_t)n * 4, stream);
  hipMemsetAsync(as2, 0, (size_t)n * 4, stream);
  hipMemsetAsync(ad2, 0, (size_t)n * 4, stream);
  hist_kernel<<<2048, 256, 0, stream>>>(eidx, deg, nE, n);
  int nb = (n + SCAN_CHUNK - 1) / SCAN_CHUNK;  // 49 (<=64 required)
  scan_partial<<<nb, 256, 0, stream>>>(deg, bsum, n);
  scan_bsums<<<1, 64, 0, stream>>>(bsum, bscan, offs, nb, n);
  scan_final<<<nb, 256, 0, stream>>>(deg, bscan, offs, cursor, n);
  scatter_kernel<<<2048, 256, 0, stream>>>(eidx, cursor, csr, nE, n);

  const int mtiles = (n + 63) / 64;  // 782
  const int BIGK = 1 << 30;

  // 2. h1b = bf16(x @ W_g1), as1/ad1 fused
  gemm_bf<true><<<dim3(mtiles, 2), 256, 0, stream>>>(
      x, x, BIGK, GIN, GIN, W_g1, 0, GHID, h1b, GHID,
      a1_src, a1_dst, as1, ad1, n, GIN);

  // 3. f1 = relu(agg(h1b) + b_g1)
  gat_agg1<<<(n + 3) / 4, 256, 0, stream>>>(h1b, as1, ad1, offs, csr, b_g1, f1, n);

  // 4. h2b = bf16(f1 @ W_g2), as2/ad2 fused
  gemm_bf<true><<<dim3(mtiles, 1), 256, 0, stream>>>(
      f1, f1, BIGK, GHID, GHID, W_g2, 0, GOUT, h2b, GOUT,
      a2_src, a2_dst, as2, ad2, n, GHID);

  // 5. f2 = relu(agg(h2b) + b_g2)
  gat_agg2<<<(n + 3) / 4, 256, 0, stream>>>(h2b, as2, ad2, offs, csr, b_g2, f2, n);

  // 6. Pb = bf16([x|f2] @ W_m1[0:256]) — one dispatch, k-split A, B row-chunk
  gemm_bf<false><<<dim3(mtiles, 4), 256, 0, stream>>>(
      x, f2, GIN, GIN, GOUT, W_m1, 128 * 128, GHID, Pb, 256,
      nullptr, nullptr, nullptr, nullptr, n, GHID);

  // 7. fused edge MLP + sigmoid (original edge order)
  edge_mlp<<<4096, 256, 0, stream>>>((const int2*)eidx, dist, Pb,
                                     W_m1 + 256 * 128, b_m1, W_m2, b_m2, out, nE);
}

// Round 9
// 590.548 us; speedup vs baseline: 1.3230x; 1.1032x over previous
//
#include <hip/hip_runtime.h>
#include <hip/hip_bf16.h>
#include <math.h>

// ---------------------------------------------------------------------------
// GATEdgeNet. fp32 compute; gathered tensors (h1, h2, P) stored bf16.
// CSR build is XCD-partitioned: cohort (blockIdx%8) owns dst range r, so all
// csr/cursor writes for a range come from ONE XCD -> no L2 line ping-pong
// (round 7 showed 16x write amplification from cross-XCD scatter).
// Self-loops occupy slot 0 of each node's CSR segment (no atomics).
//   1. partitioned hist (+1 self-loop folded into scan) / scan / part. scatter
//   2. h1b = bf16(x @ W_g1); as1/ad1 fused in GEMM epilogue (fp32-exact)
//   3. f1 = relu(agg(h1b) + b_g1)   -- no max pass (exp(e) bounded, ratio exact)
//   4. h2b = bf16(f1 @ W_g2); as2/ad2 fused
//   5. f2 = relu(agg(h2b) + b_g2)
//   6. Pb = bf16([x|f2] @ W_m1[0:256])   (one dispatch, k-split A source)
//   7. edge MLP in original edge order (streamed eidx/dist/out, random P)
// ---------------------------------------------------------------------------

#define GIN 64
#define GHID 128
#define GOUT 64

typedef unsigned int u32;
typedef unsigned short u16;

__device__ __forceinline__ float bflo(u32 u) {
  union { u32 i; float f; } c; c.i = u << 16; return c.f;
}
__device__ __forceinline__ float bfhi(u32 u) {
  union { u32 i; float f; } c; c.i = u & 0xffff0000u; return c.f;
}
__device__ __forceinline__ u16 f2bf(float x) {
  __hip_bfloat16 h = __float2bfloat16(x);
  return *reinterpret_cast<u16*>(&h);
}

// ---------------- CSR build: XCD-partitioned hist + scatter ----------------
// cohort r = blockIdx & 7 owns dst in [r*nper, min(n,(r+1)*nper)).
// Each cohort streams the full edge list (int2: both directions per load).

__global__ void hist_part(const int2* __restrict__ eidx2, int* __restrict__ deg,
                          int nE, int n) {
  int r = blockIdx.x & 7;
  int nper = (n + 7) >> 3;
  int r0 = r * nper;
  int r1 = min(n, r0 + nper);
  u32 span = (u32)(r1 - r0);
  int cb = blockIdx.x >> 3, nb = gridDim.x >> 3;
  for (int e = cb * blockDim.x + threadIdx.x; e < nE; e += nb * blockDim.x) {
    int2 rc = eidx2[e];
    if ((u32)(rc.y - r0) < span) atomicAdd(&deg[rc.y], 1);  // forward: dst=c
    if ((u32)(rc.x - r0) < span) atomicAdd(&deg[rc.x], 1);  // reverse: dst=r
  }
}

// scans treat node degree as deg[i]+1 (self-loop occupies slot 0)
#define SCAN_CHUNK 1024
__global__ void scan_partial(const int* __restrict__ deg, int* __restrict__ bsum,
                             int n) {
  int b = blockIdx.x, tid = threadIdx.x;  // 256 threads
  int base = b * SCAN_CHUNK + tid * 4;
  int s = 0;
#pragma unroll
  for (int c = 0; c < 4; ++c) { int i = base + c; if (i < n) s += deg[i] + 1; }
#pragma unroll
  for (int off = 32; off; off >>= 1) s += __shfl_xor(s, off, 64);
  __shared__ int ws[4];
  if ((tid & 63) == 0) ws[tid >> 6] = s;
  __syncthreads();
  if (tid == 0) bsum[b] = ws[0] + ws[1] + ws[2] + ws[3];
}
__global__ void scan_bsums(const int* __restrict__ bsum, int* __restrict__ bscan,
                           int* __restrict__ offs, int nb, int n) {
  int lane = threadIdx.x;
  int v = (lane < nb) ? bsum[lane] : 0;
  int incl = v;
#pragma unroll
  for (int off = 1; off < 64; off <<= 1) {
    int t = __shfl_up(incl, off, 64);
    if (lane >= off) incl += t;
  }
  if (lane < nb) bscan[lane] = incl - v;
  if (lane == 63) offs[n] = incl;
}
__global__ void scan_final(const int* __restrict__ deg, const int* __restrict__ bscan,
                           int* __restrict__ offs, int* __restrict__ cursor, int n) {
  int b = blockIdx.x, tid = threadIdx.x;
  int base = b * SCAN_CHUNK + tid * 4;
  int v[4]; int s = 0;
#pragma unroll
  for (int c = 0; c < 4; ++c) {
    int i = base + c;
    v[c] = (i < n) ? deg[i] + 1 : 0;
    s += v[c];
  }
  int lane = tid & 63, wv = tid >> 6;
  int incl = s;
#pragma unroll
  for (int off = 1; off < 64; off <<= 1) {
    int t = __shfl_up(incl, off, 64);
    if (lane >= off) incl += t;
  }
  __shared__ int ws[4];
  if (lane == 63) ws[wv] = incl;
  __syncthreads();
  int woff = 0;
  for (int w2 = 0; w2 < wv; ++w2) woff += ws[w2];
  int excl = bscan[b] + woff + incl - s;
#pragma unroll
  for (int c = 0; c < 4; ++c) {
    int i = base + c;
    if (i < n) { offs[i] = excl; cursor[i] = excl + 1; }  // slot 0 = self-loop
    excl += v[c];
  }
}

__global__ void scatter_part(const int2* __restrict__ eidx2,
                             const int* __restrict__ offs, int* __restrict__ cursor,
                             int* __restrict__ csr, int nE, int n) {
  int r = blockIdx.x & 7;
  int nper = (n + 7) >> 3;
  int r0 = r * nper;
  int r1 = min(n, r0 + nper);
  u32 span = (u32)(r1 - r0);
  int cb = blockIdx.x >> 3, nb = gridDim.x >> 3;
  // self-loops into reserved slot 0 (no atomic)
  for (int i = r0 + cb * blockDim.x + threadIdx.x; i < r1; i += nb * blockDim.x)
    csr[offs[i]] = i;
  // both edge directions from one int2 load
  for (int e = cb * blockDim.x + threadIdx.x; e < nE; e += nb * blockDim.x) {
    int2 rc = eidx2[e];
    if ((u32)(rc.y - r0) < span) { int pos = atomicAdd(&cursor[rc.y], 1); csr[pos] = rc.x; }
    if ((u32)(rc.x - r0) < span) { int pos = atomicAdd(&cursor[rc.x], 1); csr[pos] = rc.y; }
  }
}

// ---- fp32 GEMM, bf16 store, optional fused score dots, k-split A source ----

template <bool SCORES>
__global__ __launch_bounds__(256) void gemm_bf(
    const float* __restrict__ A, const float* __restrict__ A2, int ksp,
    int lda, int lda2,
    const float* __restrict__ B, int bskip, int ldb,
    u16* __restrict__ Cb, int ldcb,
    const float* __restrict__ av, const float* __restrict__ bv,
    float* __restrict__ as_, float* __restrict__ ad_,
    int M, int K) {
  __shared__ float As[32][68];   // 68 floats: rows 16B-aligned (17*16B)
  __shared__ float Bs[32][64];
  int tid = threadIdx.x;
  int m0 = blockIdx.x * 64;
  int n0 = blockIdx.y * 64;
  const float* Bp = B + (size_t)(n0 >> 7) * bskip;  // W_m1 row-chunk select
  int nb0 = n0 & 127;
  int tx = tid & 15, ty = tid >> 4;
  float acc[4][4] = {};
  for (int k0 = 0; k0 < K; k0 += 32) {
    const float* Asrc; int Alda; int kk;
    if (k0 < ksp) { Asrc = A;  Alda = lda;  kk = k0; }
    else          { Asrc = A2; Alda = lda2; kk = k0 - ksp; }
#pragma unroll
    for (int r = 0; r < 2; ++r) {   // A tile 64x32
      int m = (tid >> 3) + r * 32;
      int k = (tid & 7) * 4;
      float4 v = make_float4(0.f, 0.f, 0.f, 0.f);
      int gm = m0 + m;
      if (gm < M) v = *reinterpret_cast<const float4*>(&Asrc[(size_t)gm * Alda + kk + k]);
      As[k + 0][m] = v.x; As[k + 1][m] = v.y; As[k + 2][m] = v.z; As[k + 3][m] = v.w;
    }
#pragma unroll
    for (int r = 0; r < 2; ++r) {   // B tile 32x64
      int k = (tid >> 4) + r * 16;
      int nn = (tid & 15) * 4;
      float4 v = *reinterpret_cast<const float4*>(&Bp[(size_t)(k0 + k) * ldb + nb0 + nn]);
      *reinterpret_cast<float4*>(&Bs[k][nn]) = v;
    }
    __syncthreads();
#pragma unroll
    for (int k = 0; k < 32; ++k) {
      float a[4], b[4];
#pragma unroll
      for (int i = 0; i < 4; ++i) a[i] = As[k][ty * 4 + i];
#pragma unroll
      for (int i = 0; i < 4; ++i) b[i] = Bs[k][tx * 4 + i];
#pragma unroll
      for (int i = 0; i < 4; ++i)
#pragma unroll
        for (int j = 0; j < 4; ++j) acc[i][j] += a[i] * b[j];
    }
    __syncthreads();
  }
  float avv[4], bvv[4];
  if constexpr (SCORES) {
#pragma unroll
    for (int j = 0; j < 4; ++j) {
      avv[j] = av[n0 + tx * 4 + j];
      bvv[j] = bv[n0 + tx * 4 + j];
    }
  }
#pragma unroll
  for (int i = 0; i < 4; ++i) {
    int gm = m0 + ty * 4 + i;
    bool inb = gm < M;
    if (inb) {
      u16* bp = &Cb[(size_t)gm * ldcb + n0 + tx * 4];
      *reinterpret_cast<ushort4*>(bp) = make_ushort4(
          f2bf(acc[i][0]), f2bf(acc[i][1]), f2bf(acc[i][2]), f2bf(acc[i][3]));
    }
    if constexpr (SCORES) {
      float ps = acc[i][0] * avv[0] + acc[i][1] * avv[1] +
                 acc[i][2] * avv[2] + acc[i][3] * avv[3];
      float pd = acc[i][0] * bvv[0] + acc[i][1] * bvv[1] +
                 acc[i][2] * bvv[2] + acc[i][3] * bvv[3];
#pragma unroll
      for (int off = 1; off < 16; off <<= 1) {
        ps += __shfl_xor(ps, off, 16);
        pd += __shfl_xor(pd, off, 16);
      }
      if (tx == 0 && inb) {
        atomicAdd(&as_[gm], ps);
        atomicAdd(&ad_[gm], pd);
      }
    }
  }
}

// ---- GAT agg, D=128: 8 edge slots/wave (8 lanes/edge), 2-level pipeline ---

__global__ __launch_bounds__(256) void gat_agg1(
    const u16* __restrict__ hb, const float* __restrict__ as_,
    const float* __restrict__ ad_, const int* __restrict__ offs,
    const int* __restrict__ csr, const float* __restrict__ bias,
    float* __restrict__ out, int n) {
  int node = blockIdx.x * 4 + (threadIdx.x >> 6);
  if (node >= n) return;
  int lane = threadIdx.x & 63;
  int g = lane >> 3, sl = lane & 7;   // 8 slots, lane covers cols sl*16..+15
  int beg = offs[node], end = offs[node + 1];
  float adn = ad_[node];
  float denom = 0.f;
  float a[16] = {};
  int i0 = beg + g;
  int s0 = (i0 < end) ? csr[i0] : -1;
  uint4 pa0 = make_uint4(0,0,0,0), pb0 = make_uint4(0,0,0,0); float e0 = 0.f;
  if (s0 >= 0) {
    const u16* row = &hb[(size_t)s0 * 128 + sl * 16];
    pa0 = *reinterpret_cast<const uint4*>(row);
    pb0 = *reinterpret_cast<const uint4*>(row + 8);
    e0 = as_[s0] + adn;
  }
  int i1 = i0 + 8;
  int s1 = (i1 < end) ? csr[i1] : -1;
  while (s0 >= 0) {
    int i2 = i1 + 8;
    int s2 = (i2 < end) ? csr[i2] : -1;          // index 2 ahead
    uint4 pa1 = make_uint4(0,0,0,0), pb1 = make_uint4(0,0,0,0); float e1 = 0.f;
    if (s1 >= 0) {                               // data 1 ahead (addr resident)
      const u16* row = &hb[(size_t)s1 * 128 + sl * 16];
      pa1 = *reinterpret_cast<const uint4*>(row);
      pb1 = *reinterpret_cast<const uint4*>(row + 8);
      e1 = as_[s1] + adn;
    }
    float e = (e0 > 0.f) ? e0 : 0.2f * e0;
    float wgt = __expf(e);
    denom += wgt;
    a[0]  += wgt * bflo(pa0.x); a[1]  += wgt * bfhi(pa0.x);
    a[2]  += wgt * bflo(pa0.y); a[3]  += wgt * bfhi(pa0.y);
    a[4]  += wgt * bflo(pa0.z); a[5]  += wgt * bfhi(pa0.z);
    a[6]  += wgt * bflo(pa0.w); a[7]  += wgt * bfhi(pa0.w);
    a[8]  += wgt * bflo(pb0.x); a[9]  += wgt * bfhi(pb0.x);
    a[10] += wgt * bflo(pb0.y); a[11] += wgt * bfhi(pb0.y);
    a[12] += wgt * bflo(pb0.z); a[13] += wgt * bfhi(pb0.z);
    a[14] += wgt * bflo(pb0.w); a[15] += wgt * bfhi(pb0.w);
    s0 = s1; pa0 = pa1; pb0 = pb1; e0 = e1;
    s1 = s2; i1 = i2;
  }
  denom += __shfl_xor(denom, 8, 64);
  denom += __shfl_xor(denom, 16, 64);
  denom += __shfl_xor(denom, 32, 64);
#pragma unroll
  for (int j = 0; j < 16; ++j) {
    a[j] += __shfl_xor(a[j], 8, 64);
    a[j] += __shfl_xor(a[j], 16, 64);
    a[j] += __shfl_xor(a[j], 32, 64);
  }
  if (g == 0) {
    float inv = 1.f / (denom + 1e-16f);
    float* op = &out[(size_t)node * 128 + sl * 16];
    const float* bp = &bias[sl * 16];
#pragma unroll
    for (int q = 0; q < 4; ++q) {
      float4 bq = *reinterpret_cast<const float4*>(bp + q * 4);
      float4 o;
      o.x = fmaxf(a[q * 4 + 0] * inv + bq.x, 0.f);
      o.y = fmaxf(a[q * 4 + 1] * inv + bq.y, 0.f);
      o.z = fmaxf(a[q * 4 + 2] * inv + bq.z, 0.f);
      o.w = fmaxf(a[q * 4 + 3] * inv + bq.w, 0.f);
      *reinterpret_cast<float4*>(op + q * 4) = o;
    }
  }
}

// ---- GAT agg, D=64: 16 edge slots/wave (4 lanes/edge), 2-level pipeline ---

__global__ __launch_bounds__(256) void gat_agg2(
    const u16* __restrict__ hb, const float* __restrict__ as_,
    const float* __restrict__ ad_, const int* __restrict__ offs,
    const int* __restrict__ csr, const float* __restrict__ bias,
    float* __restrict__ out, int n) {
  int node = blockIdx.x * 4 + (threadIdx.x >> 6);
  if (node >= n) return;
  int lane = threadIdx.x & 63;
  int g = lane >> 2, sl = lane & 3;   // 16 slots, lane covers cols sl*16..+15
  int beg = offs[node], end = offs[node + 1];
  float adn = ad_[node];
  float denom = 0.f;
  float a[16] = {};
  int i0 = beg + g;
  int s0 = (i0 < end) ? csr[i0] : -1;
  uint4 pa0 = make_uint4(0,0,0,0), pb0 = make_uint4(0,0,0,0); float e0 = 0.f;
  if (s0 >= 0) {
    const u16* row = &hb[(size_t)s0 * 64 + sl * 16];
    pa0 = *reinterpret_cast<const uint4*>(row);
    pb0 = *reinterpret_cast<const uint4*>(row + 8);
    e0 = as_[s0] + adn;
  }
  int i1 = i0 + 16;
  int s1 = (i1 < end) ? csr[i1] : -1;
  while (s0 >= 0) {
    int i2 = i1 + 16;
    int s2 = (i2 < end) ? csr[i2] : -1;
    uint4 pa1 = make_uint4(0,0,0,0), pb1 = make_uint4(0,0,0,0); float e1 = 0.f;
    if (s1 >= 0) {
      const u16* row = &hb[(size_t)s1 * 64 + sl * 16];
      pa1 = *reinterpret_cast<const uint4*>(row);
      pb1 = *reinterpret_cast<const uint4*>(row + 8);
      e1 = as_[s1] + adn;
    }
    float e = (e0 > 0.f) ? e0 : 0.2f * e0;
    float wgt = __expf(e);
    denom += wgt;
    a[0]  += wgt * bflo(pa0.x); a[1]  += wgt * bfhi(pa0.x);
    a[2]  += wgt * bflo(pa0.y); a[3]  += wgt * bfhi(pa0.y);
    a[4]  += wgt * bflo(pa0.z); a[5]  += wgt * bfhi(pa0.z);
    a[6]  += wgt * bflo(pa0.w); a[7]  += wgt * bfhi(pa0.w);
    a[8]  += wgt * bflo(pb0.x); a[9]  += wgt * bfhi(pb0.x);
    a[10] += wgt * bflo(pb0.y); a[11] += wgt * bfhi(pb0.y);
    a[12] += wgt * bflo(pb0.z); a[13] += wgt * bfhi(pb0.z);
    a[14] += wgt * bflo(pb0.w); a[15] += wgt * bfhi(pb0.w);
    s0 = s1; pa0 = pa1; pb0 = pb1; e0 = e1;
    s1 = s2; i1 = i2;
  }
#pragma unroll
  for (int w2 = 4; w2 < 64; w2 <<= 1) denom += __shfl_xor(denom, w2, 64);
#pragma unroll
  for (int j = 0; j < 16; ++j) {
    a[j] += __shfl_xor(a[j], 4, 64);
    a[j] += __shfl_xor(a[j], 8, 64);
    a[j] += __shfl_xor(a[j], 16, 64);
    a[j] += __shfl_xor(a[j], 32, 64);
  }
  if (g == 0) {
    float inv = 1.f / (denom + 1e-16f);
    float* op = &out[(size_t)node * 64 + sl * 16];
    const float* bp = &bias[sl * 16];
#pragma unroll
    for (int q = 0; q < 4; ++q) {
      float4 bq = *reinterpret_cast<const float4*>(bp + q * 4);
      float4 o;
      o.x = fmaxf(a[q * 4 + 0] * inv + bq.x, 0.f);
      o.y = fmaxf(a[q * 4 + 1] * inv + bq.y, 0.f);
      o.z = fmaxf(a[q * 4 + 2] * inv + bq.z, 0.f);
      o.w = fmaxf(a[q * 4 + 3] * inv + bq.w, 0.f);
      *reinterpret_cast<float4*>(op + q * 4) = o;
    }
  }
}

// ---- fused edge MLP: original edge order, 4 edges/wave, 2-level pipeline --

__global__ __launch_bounds__(256) void edge_mlp(
    const int2* __restrict__ eidx, const float* __restrict__ dist,
    const u16* __restrict__ Pb, const float* __restrict__ W3,
    const float* __restrict__ b1, const float* __restrict__ W2,
    const float* __restrict__ b2, float* __restrict__ out, int nE) {
  __shared__ float4 W3s[16][32];  // [k][q]: cols q*4..q*4+3
  int tid = threadIdx.x;
  for (int idx = tid; idx < 16 * 32; idx += 256) {
    int k = idx >> 5, q = idx & 31;
    W3s[k][q] = *reinterpret_cast<const float4*>(&W3[k * 128 + q * 4]);
  }
  __syncthreads();
  int lane = tid & 63, wv = tid >> 6;
  int g = lane >> 4, sl = lane & 15;   // edge slot g, 8 cols per lane
  float4 b1a = *reinterpret_cast<const float4*>(&b1[sl * 8]);
  float4 b1b = *reinterpret_cast<const float4*>(&b1[sl * 8 + 4]);
  float4 w2a = *reinterpret_cast<const float4*>(&W2[sl * 8]);
  float4 w2b = *reinterpret_cast<const float4*>(&W2[sl * 8 + 4]);
  float b2v = b2[0];
  const int stride = gridDim.x * 16;
  int e0 = (blockIdx.x * 4 + wv) * 4 + g;
  bool v0 = e0 < nE;
  int2 rc0 = v0 ? eidx[e0] : make_int2(0, 0);
  uint4 p1 = make_uint4(0,0,0,0), p2 = make_uint4(0,0,0,0); float ds0 = 0.f;
  if (v0) {
    p1 = *reinterpret_cast<const uint4*>(&Pb[(size_t)rc0.x * 256 + sl * 8]);
    p2 = *reinterpret_cast<const uint4*>(&Pb[(size_t)rc0.y * 256 + 128 + sl * 8]);
    ds0 = dist[(size_t)e0 * 16 + sl];
  }
  int e1 = e0 + stride;
  bool v1 = e1 < nE;
  int2 rc1 = v1 ? eidx[e1] : make_int2(0, 0);
  while (v0) {
    int e2 = e1 + stride;
    bool v2 = e2 < nE;
    int2 rc2 = v2 ? eidx[e2] : make_int2(0, 0);     // index 2 ahead
    uint4 q1 = make_uint4(0,0,0,0), q2 = make_uint4(0,0,0,0); float ds1 = 0.f;
    if (v1) {                                        // data 1 ahead
      q1 = *reinterpret_cast<const uint4*>(&Pb[(size_t)rc1.x * 256 + sl * 8]);
      q2 = *reinterpret_cast<const uint4*>(&Pb[(size_t)rc1.y * 256 + 128 + sl * 8]);
      ds1 = dist[(size_t)e1 * 16 + sl];
    }
    float a[8];
    a[0] = bflo(p1.x) + bflo(p2.x) + b1a.x;
    a[1] = bfhi(p1.x) + bfhi(p2.x) + b1a.y;
    a[2] = bflo(p1.y) + bflo(p2.y) + b1a.z;
    a[3] = bfhi(p1.y) + bfhi(p2.y) + b1a.w;
    a[4] = bflo(p1.z) + bflo(p2.z) + b1b.x;
    a[5] = bfhi(p1.z) + bfhi(p2.z) + b1b.y;
    a[6] = bflo(p1.w) + bflo(p2.w) + b1b.z;
    a[7] = bfhi(p1.w) + bfhi(p2.w) + b1b.w;
#pragma unroll
    for (int k = 0; k < 16; ++k) {
      float dk = __shfl(ds0, (g << 4) + k, 64);
      float4 wA = W3s[k][2 * sl];
      float4 wB = W3s[k][2 * sl + 1];
      a[0] += dk * wA.x; a[1] += dk * wA.y; a[2] += dk * wA.z; a[3] += dk * wA.w;
      a[4] += dk * wB.x; a[5] += dk * wB.y; a[6] += dk * wB.z; a[7] += dk * wB.w;
    }
    float p_ = fmaxf(a[0], 0.f) * w2a.x + fmaxf(a[1], 0.f) * w2a.y +
               fmaxf(a[2], 0.f) * w2a.z + fmaxf(a[3], 0.f) * w2a.w +
               fmaxf(a[4], 0.f) * w2b.x + fmaxf(a[5], 0.f) * w2b.y +
               fmaxf(a[6], 0.f) * w2b.z + fmaxf(a[7], 0.f) * w2b.w;
#pragma unroll
    for (int off = 1; off < 16; off <<= 1) p_ += __shfl_xor(p_, off, 16);
    if (sl == 0) out[e0] = 1.f / (1.f + __expf(-(p_ + b2v)));
    e0 = e1; v0 = v1; p1 = q1; p2 = q2; ds0 = ds1;
    e1 = e2; v1 = v2; rc1 = rc2;
  }
}

// ---------------- launch ---------------------------------------------------

extern "C" void kernel_launch(void* const* d_in, const int* in_sizes, int n_in,
                              void* d_out, int out_size, void* d_ws, size_t ws_size,
                              hipStream_t stream) {
  const float* x      = (const float*)d_in[0];
  const int*   eidx   = (const int*)d_in[1];
  const float* dist   = (const float*)d_in[2];
  const float* W_g1   = (const float*)d_in[3];
  const float* a1_src = (const float*)d_in[4];
  const float* a1_dst = (const float*)d_in[5];
  const float* b_g1   = (const float*)d_in[6];
  const float* W_g2   = (const float*)d_in[7];
  const float* a2_src = (const float*)d_in[8];
  const float* a2_dst = (const float*)d_in[9];
  const float* b_g2   = (const float*)d_in[10];
  const float* W_m1   = (const float*)d_in[11];
  const float* b_m1   = (const float*)d_in[12];
  const float* W_m2   = (const float*)d_in[13];
  const float* b_m2   = (const float*)d_in[14];
  float* out = (float*)d_out;

  const int n  = in_sizes[0] / GIN;   // 50000
  const int nE = in_sizes[1] / 2;     // 800000
  const int ndir = 2 * nE + n;        // 1,650,000

  char* w = (char*)d_ws;
  size_t off = 0;
  auto alloc = [&](size_t bytes) {
    size_t o = off;
    off += (bytes + 255) & ~(size_t)255;
    return o;
  };
  size_t o_deg    = alloc((size_t)n * 4);
  size_t o_offs   = alloc((size_t)(n + 1) * 4);
  size_t o_cursor = alloc((size_t)n * 4);
  size_t o_as1    = alloc((size_t)n * 4);
  size_t o_ad1    = alloc((size_t)n * 4);
  size_t o_as2    = alloc((size_t)n * 4);
  size_t o_ad2    = alloc((size_t)n * 4);
  size_t o_bsum   = alloc(64 * 4);
  size_t o_bscan  = alloc(64 * 4);
  size_t o_csr    = alloc((size_t)ndir * 4);
  size_t o_big    = alloc((size_t)n * 256 * 2);  // Pb; h1b/h2b overlay
  size_t o_f1     = alloc((size_t)n * GHID * 4);
  size_t o_f2     = alloc((size_t)n * GOUT * 4);
  (void)ws_size;

  int*   deg    = (int*)(w + o_deg);
  int*   offs   = (int*)(w + o_offs);
  int*   cursor = (int*)(w + o_cursor);
  float* as1    = (float*)(w + o_as1);
  float* ad1    = (float*)(w + o_ad1);
  float* as2    = (float*)(w + o_as2);
  float* ad2    = (float*)(w + o_ad2);
  int*   bsum   = (int*)(w + o_bsum);
  int*   bscan  = (int*)(w + o_bscan);
  int*   csr    = (int*)(w + o_csr);
  u16*   h1b    = (u16*)(w + o_big);                          // dead after agg1
  u16*   h2b    = (u16*)(w + o_big + (size_t)n * GHID * 2);   // dead after agg2
  u16*   Pb     = (u16*)(w + o_big);                          // overlays h1b/h2b
  float* f1     = (float*)(w + o_f1);
  float* f2     = (float*)(w + o_f2);

  // 1. XCD-partitioned CSR build + score-accumulator zeroing
  hipMemsetAsync(deg, 0, (size_t)n * 4, stream);
  hipMemsetAsync(as1, 0, (size_t)n * 4, stream);
  hipMemsetAsync(ad1, 0, (size_t)n * 4, stream);
  hipMemsetAsync(as2, 0, (size_t)n * 4, stream);
  hipMemsetAsync(ad2, 0, (size_t)n * 4, stream);
  hist_part<<<2048, 256, 0, stream>>>((const int2*)eidx, deg, nE, n);
  int nb = (n + SCAN_CHUNK - 1) / SCAN_CHUNK;  // 49 (<=64 required)
  scan_partial<<<nb, 256, 0, stream>>>(deg, bsum, n);
  scan_bsums<<<1, 64, 0, stream>>>(bsum, bscan, offs, nb, n);
  scan_final<<<nb, 256, 0, stream>>>(deg, bscan, offs, cursor, n);
  scatter_part<<<2048, 256, 0, stream>>>((const int2*)eidx, offs, cursor, csr, nE, n);

  const int mtiles = (n + 63) / 64;  // 782
  const int BIGK = 1 << 30;

  // 2. h1b = bf16(x @ W_g1), as1/ad1 fused
  gemm_bf<true><<<dim3(mtiles, 2), 256, 0, stream>>>(
      x, x, BIGK, GIN, GIN, W_g1, 0, GHID, h1b, GHID,
      a1_src, a1_dst, as1, ad1, n, GIN);

  // 3. f1 = relu(agg(h1b) + b_g1)
  gat_agg1<<<(n + 3) / 4, 256, 0, stream>>>(h1b, as1, ad1, offs, csr, b_g1, f1, n);

  // 4. h2b = bf16(f1 @ W_g2), as2/ad2 fused
  gemm_bf<true><<<dim3(mtiles, 1), 256, 0, stream>>>(
      f1, f1, BIGK, GHID, GHID, W_g2, 0, GOUT, h2b, GOUT,
      a2_src, a2_dst, as2, ad2, n, GHID);

  // 5. f2 = relu(agg(h2b) + b_g2)
  gat_agg2<<<(n + 3) / 4, 256, 0, stream>>>(h2b, as2, ad2, offs, csr, b_g2, f2, n);

  // 6. Pb = bf16([x|f2] @ W_m1[0:256]) — one dispatch, k-split A, B row-chunk
  gemm_bf<false><<<dim3(mtiles, 4), 256, 0, stream>>>(
      x, f2, GIN, GIN, GOUT, W_m1, 128 * 128, GHID, Pb, 256,
      nullptr, nullptr, nullptr, nullptr, n, GHID);

  // 7. fused edge MLP + sigmoid (original edge order)
  edge_mlp<<<4096, 256, 0, stream>>>((const int2*)eidx, dist, Pb,
                                     W_m1 + 256 * 128, b_m1, W_m2, b_m2, out, nE);
}

// Round 10
// 581.087 us; speedup vs baseline: 1.3445x; 1.0163x over previous
//
#include <hip/hip_runtime.h>
#include <hip/hip_bf16.h>
#include <math.h>

// ---------------------------------------------------------------------------
// GATEdgeNet. fp32 compute; gathered tensors (h1, h2, P) stored bf16.
// CSR build is XCD-partitioned (round 7 lesson: cross-XCD 4B scatter = 16x
// write amplification). Gather kernels use 3-stage software pipelines
// (data 2 ahead, index 3 ahead) to double outstanding loads per wave.
//   1. partitioned hist (+1 self-loop folded into scan) / scan / part. scatter
//   2. h1b = bf16(x @ W_g1); as1/ad1 fused in GEMM epilogue (fp32-exact)
//   3. f1 = relu(agg(h1b) + b_g1)   -- no max pass (exp(e) bounded, ratio exact)
//   4. h2b = bf16(f1 @ W_g2); as2/ad2 fused
//   5. f2 = relu(agg(h2b) + b_g2)
//   6. Pb = bf16([x|f2] @ W_m1[0:256])   (one dispatch, k-split A source)
//   7. edge MLP in original edge order (streamed eidx/dist/out, random P)
// ---------------------------------------------------------------------------

#define GIN 64
#define GHID 128
#define GOUT 64

typedef unsigned int u32;
typedef unsigned short u16;

__device__ __forceinline__ float bflo(u32 u) {
  union { u32 i; float f; } c; c.i = u << 16; return c.f;
}
__device__ __forceinline__ float bfhi(u32 u) {
  union { u32 i; float f; } c; c.i = u & 0xffff0000u; return c.f;
}
__device__ __forceinline__ u16 f2bf(float x) {
  __hip_bfloat16 h = __float2bfloat16(x);
  return *reinterpret_cast<u16*>(&h);
}

// ---------------- CSR build: XCD-partitioned hist + scatter ----------------

__global__ void hist_part(const int2* __restrict__ eidx2, int* __restrict__ deg,
                          int nE, int n) {
  int r = blockIdx.x & 7;
  int nper = (n + 7) >> 3;
  int r0 = r * nper;
  int r1 = min(n, r0 + nper);
  u32 span = (u32)(r1 - r0);
  int cb = blockIdx.x >> 3, nb = gridDim.x >> 3;
  for (int e = cb * blockDim.x + threadIdx.x; e < nE; e += nb * blockDim.x) {
    int2 rc = eidx2[e];
    if ((u32)(rc.y - r0) < span) atomicAdd(&deg[rc.y], 1);
    if ((u32)(rc.x - r0) < span) atomicAdd(&deg[rc.x], 1);
  }
}

#define SCAN_CHUNK 1024
__global__ void scan_partial(const int* __restrict__ deg, int* __restrict__ bsum,
                             int n) {
  int b = blockIdx.x, tid = threadIdx.x;
  int base = b * SCAN_CHUNK + tid * 4;
  int s = 0;
#pragma unroll
  for (int c = 0; c < 4; ++c) { int i = base + c; if (i < n) s += deg[i] + 1; }
#pragma unroll
  for (int off = 32; off; off >>= 1) s += __shfl_xor(s, off, 64);
  __shared__ int ws[4];
  if ((tid & 63) == 0) ws[tid >> 6] = s;
  __syncthreads();
  if (tid == 0) bsum[b] = ws[0] + ws[1] + ws[2] + ws[3];
}
__global__ void scan_bsums(const int* __restrict__ bsum, int* __restrict__ bscan,
                           int* __restrict__ offs, int nb, int n) {
  int lane = threadIdx.x;
  int v = (lane < nb) ? bsum[lane] : 0;
  int incl = v;
#pragma unroll
  for (int off = 1; off < 64; off <<= 1) {
    int t = __shfl_up(incl, off, 64);
    if (lane >= off) incl += t;
  }
  if (lane < nb) bscan[lane] = incl - v;
  if (lane == 63) offs[n] = incl;
}
__global__ void scan_final(const int* __restrict__ deg, const int* __restrict__ bscan,
                           int* __restrict__ offs, int* __restrict__ cursor, int n) {
  int b = blockIdx.x, tid = threadIdx.x;
  int base = b * SCAN_CHUNK + tid * 4;
  int v[4]; int s = 0;
#pragma unroll
  for (int c = 0; c < 4; ++c) {
    int i = base + c;
    v[c] = (i < n) ? deg[i] + 1 : 0;
    s += v[c];
  }
  int lane = tid & 63, wv = tid >> 6;
  int incl = s;
#pragma unroll
  for (int off = 1; off < 64; off <<= 1) {
    int t = __shfl_up(incl, off, 64);
    if (lane >= off) incl += t;
  }
  __shared__ int ws[4];
  if (lane == 63) ws[wv] = incl;
  __syncthreads();
  int woff = 0;
  for (int w2 = 0; w2 < wv; ++w2) woff += ws[w2];
  int excl = bscan[b] + woff + incl - s;
#pragma unroll
  for (int c = 0; c < 4; ++c) {
    int i = base + c;
    if (i < n) { offs[i] = excl; cursor[i] = excl + 1; }  // slot 0 = self-loop
    excl += v[c];
  }
}

__global__ void scatter_part(const int2* __restrict__ eidx2,
                             const int* __restrict__ offs, int* __restrict__ cursor,
                             int* __restrict__ csr, int nE, int n) {
  int r = blockIdx.x & 7;
  int nper = (n + 7) >> 3;
  int r0 = r * nper;
  int r1 = min(n, r0 + nper);
  u32 span = (u32)(r1 - r0);
  int cb = blockIdx.x >> 3, nb = gridDim.x >> 3;
  for (int i = r0 + cb * blockDim.x + threadIdx.x; i < r1; i += nb * blockDim.x)
    csr[offs[i]] = i;
  for (int e = cb * blockDim.x + threadIdx.x; e < nE; e += nb * blockDim.x) {
    int2 rc = eidx2[e];
    if ((u32)(rc.y - r0) < span) { int pos = atomicAdd(&cursor[rc.y], 1); csr[pos] = rc.x; }
    if ((u32)(rc.x - r0) < span) { int pos = atomicAdd(&cursor[rc.x], 1); csr[pos] = rc.y; }
  }
}

// ---- fp32 GEMM, bf16 store, optional fused score dots, k-split A source ----

template <bool SCORES>
__global__ __launch_bounds__(256) void gemm_bf(
    const float* __restrict__ A, const float* __restrict__ A2, int ksp,
    int lda, int lda2,
    const float* __restrict__ B, int bskip, int ldb,
    u16* __restrict__ Cb, int ldcb,
    const float* __restrict__ av, const float* __restrict__ bv,
    float* __restrict__ as_, float* __restrict__ ad_,
    int M, int K) {
  __shared__ float As[32][68];
  __shared__ float Bs[32][64];
  int tid = threadIdx.x;
  int m0 = blockIdx.x * 64;
  int n0 = blockIdx.y * 64;
  const float* Bp = B + (size_t)(n0 >> 7) * bskip;
  int nb0 = n0 & 127;
  int tx = tid & 15, ty = tid >> 4;
  float acc[4][4] = {};
  for (int k0 = 0; k0 < K; k0 += 32) {
    const float* Asrc; int Alda; int kk;
    if (k0 < ksp) { Asrc = A;  Alda = lda;  kk = k0; }
    else          { Asrc = A2; Alda = lda2; kk = k0 - ksp; }
#pragma unroll
    for (int r = 0; r < 2; ++r) {
      int m = (tid >> 3) + r * 32;
      int k = (tid & 7) * 4;
      float4 v = make_float4(0.f, 0.f, 0.f, 0.f);
      int gm = m0 + m;
      if (gm < M) v = *reinterpret_cast<const float4*>(&Asrc[(size_t)gm * Alda + kk + k]);
      As[k + 0][m] = v.x; As[k + 1][m] = v.y; As[k + 2][m] = v.z; As[k + 3][m] = v.w;
    }
#pragma unroll
    for (int r = 0; r < 2; ++r) {
      int k = (tid >> 4) + r * 16;
      int nn = (tid & 15) * 4;
      float4 v = *reinterpret_cast<const float4*>(&Bp[(size_t)(k0 + k) * ldb + nb0 + nn]);
      *reinterpret_cast<float4*>(&Bs[k][nn]) = v;
    }
    __syncthreads();
#pragma unroll
    for (int k = 0; k < 32; ++k) {
      float a[4], b[4];
#pragma unroll
      for (int i = 0; i < 4; ++i) a[i] = As[k][ty * 4 + i];
#pragma unroll
      for (int i = 0; i < 4; ++i) b[i] = Bs[k][tx * 4 + i];
#pragma unroll
      for (int i = 0; i < 4; ++i)
#pragma unroll
        for (int j = 0; j < 4; ++j) acc[i][j] += a[i] * b[j];
    }
    __syncthreads();
  }
  float avv[4], bvv[4];
  if constexpr (SCORES) {
#pragma unroll
    for (int j = 0; j < 4; ++j) {
      avv[j] = av[n0 + tx * 4 + j];
      bvv[j] = bv[n0 + tx * 4 + j];
    }
  }
#pragma unroll
  for (int i = 0; i < 4; ++i) {
    int gm = m0 + ty * 4 + i;
    bool inb = gm < M;
    if (inb) {
      u16* bp = &Cb[(size_t)gm * ldcb + n0 + tx * 4];
      *reinterpret_cast<ushort4*>(bp) = make_ushort4(
          f2bf(acc[i][0]), f2bf(acc[i][1]), f2bf(acc[i][2]), f2bf(acc[i][3]));
    }
    if constexpr (SCORES) {
      float ps = acc[i][0] * avv[0] + acc[i][1] * avv[1] +
                 acc[i][2] * avv[2] + acc[i][3] * avv[3];
      float pd = acc[i][0] * bvv[0] + acc[i][1] * bvv[1] +
                 acc[i][2] * bvv[2] + acc[i][3] * bvv[3];
#pragma unroll
      for (int off = 1; off < 16; off <<= 1) {
        ps += __shfl_xor(ps, off, 16);
        pd += __shfl_xor(pd, off, 16);
      }
      if (tx == 0 && inb) {
        atomicAdd(&as_[gm], ps);
        atomicAdd(&ad_[gm], pd);
      }
    }
  }
}

// ---- GAT agg, D=128: 8 slots/wave (8 lanes/edge), 3-stage pipeline --------

__global__ __launch_bounds__(256) void gat_agg1(
    const u16* __restrict__ hb, const float* __restrict__ as_,
    const float* __restrict__ ad_, const int* __restrict__ offs,
    const int* __restrict__ csr, const float* __restrict__ bias,
    float* __restrict__ out, int n) {
  int node = blockIdx.x * 4 + (threadIdx.x >> 6);
  if (node >= n) return;
  int lane = threadIdx.x & 63;
  int g = lane >> 3, sl = lane & 7;   // 8 slots, lane covers cols sl*16..+15
  int beg = offs[node], end = offs[node + 1];
  float adn = ad_[node];
  float denom = 0.f;
  float a[16] = {};
  // stage0: data resident
  int i0 = beg + g;
  int s0 = (i0 < end) ? csr[i0] : -1;
  uint4 pa0 = make_uint4(0,0,0,0), pb0 = make_uint4(0,0,0,0); float e0 = 0.f;
  if (s0 >= 0) {
    const u16* row = &hb[(size_t)s0 * 128 + sl * 16];
    pa0 = *reinterpret_cast<const uint4*>(row);
    pb0 = *reinterpret_cast<const uint4*>(row + 8);
    e0 = as_[s0] + adn;
  }
  // stage1: data in flight
  int i1 = i0 + 8;
  int s1 = (i1 < end) ? csr[i1] : -1;
  uint4 pa1 = make_uint4(0,0,0,0), pb1 = make_uint4(0,0,0,0); float e1 = 0.f;
  if (s1 >= 0) {
    const u16* row = &hb[(size_t)s1 * 128 + sl * 16];
    pa1 = *reinterpret_cast<const uint4*>(row);
    pb1 = *reinterpret_cast<const uint4*>(row + 8);
    e1 = as_[s1] + adn;
  }
  // stage2: index resident
  int i2 = i1 + 8;
  int s2 = (i2 < end) ? csr[i2] : -1;
  while (s0 >= 0) {
    int i3 = i2 + 8;
    int s3 = (i3 < end) ? csr[i3] : -1;          // index 3 ahead
    uint4 pa2 = make_uint4(0,0,0,0), pb2 = make_uint4(0,0,0,0); float e2v = 0.f;
    if (s2 >= 0) {                               // data 2 ahead
      const u16* row = &hb[(size_t)s2 * 128 + sl * 16];
      pa2 = *reinterpret_cast<const uint4*>(row);
      pb2 = *reinterpret_cast<const uint4*>(row + 8);
      e2v = as_[s2] + adn;
    }
    float e = (e0 > 0.f) ? e0 : 0.2f * e0;
    float wgt = __expf(e);
    denom += wgt;
    a[0]  += wgt * bflo(pa0.x); a[1]  += wgt * bfhi(pa0.x);
    a[2]  += wgt * bflo(pa0.y); a[3]  += wgt * bfhi(pa0.y);
    a[4]  += wgt * bflo(pa0.z); a[5]  += wgt * bfhi(pa0.z);
    a[6]  += wgt * bflo(pa0.w); a[7]  += wgt * bfhi(pa0.w);
    a[8]  += wgt * bflo(pb0.x); a[9]  += wgt * bfhi(pb0.x);
    a[10] += wgt * bflo(pb0.y); a[11] += wgt * bfhi(pb0.y);
    a[12] += wgt * bflo(pb0.z); a[13] += wgt * bfhi(pb0.z);
    a[14] += wgt * bflo(pb0.w); a[15] += wgt * bfhi(pb0.w);
    s0 = s1; pa0 = pa1; pb0 = pb1; e0 = e1;
    s1 = s2; pa1 = pa2; pb1 = pb2; e1 = e2v;
    s2 = s3; i2 = i3;
  }
  denom += __shfl_xor(denom, 8, 64);
  denom += __shfl_xor(denom, 16, 64);
  denom += __shfl_xor(denom, 32, 64);
#pragma unroll
  for (int j = 0; j < 16; ++j) {
    a[j] += __shfl_xor(a[j], 8, 64);
    a[j] += __shfl_xor(a[j], 16, 64);
    a[j] += __shfl_xor(a[j], 32, 64);
  }
  if (g == 0) {
    float inv = 1.f / (denom + 1e-16f);
    float* op = &out[(size_t)node * 128 + sl * 16];
    const float* bp = &bias[sl * 16];
#pragma unroll
    for (int q = 0; q < 4; ++q) {
      float4 bq = *reinterpret_cast<const float4*>(bp + q * 4);
      float4 o;
      o.x = fmaxf(a[q * 4 + 0] * inv + bq.x, 0.f);
      o.y = fmaxf(a[q * 4 + 1] * inv + bq.y, 0.f);
      o.z = fmaxf(a[q * 4 + 2] * inv + bq.z, 0.f);
      o.w = fmaxf(a[q * 4 + 3] * inv + bq.w, 0.f);
      *reinterpret_cast<float4*>(op + q * 4) = o;
    }
  }
}

// ---- GAT agg, D=64: 16 slots/wave (4 lanes/edge), 3-stage pipeline --------

__global__ __launch_bounds__(256) void gat_agg2(
    const u16* __restrict__ hb, const float* __restrict__ as_,
    const float* __restrict__ ad_, const int* __restrict__ offs,
    const int* __restrict__ csr, const float* __restrict__ bias,
    float* __restrict__ out, int n) {
  int node = blockIdx.x * 4 + (threadIdx.x >> 6);
  if (node >= n) return;
  int lane = threadIdx.x & 63;
  int g = lane >> 2, sl = lane & 3;   // 16 slots, lane covers cols sl*16..+15
  int beg = offs[node], end = offs[node + 1];
  float adn = ad_[node];
  float denom = 0.f;
  float a[16] = {};
  int i0 = beg + g;
  int s0 = (i0 < end) ? csr[i0] : -1;
  uint4 pa0 = make_uint4(0,0,0,0), pb0 = make_uint4(0,0,0,0); float e0 = 0.f;
  if (s0 >= 0) {
    const u16* row = &hb[(size_t)s0 * 64 + sl * 16];
    pa0 = *reinterpret_cast<const uint4*>(row);
    pb0 = *reinterpret_cast<const uint4*>(row + 8);
    e0 = as_[s0] + adn;
  }
  int i1 = i0 + 16;
  int s1 = (i1 < end) ? csr[i1] : -1;
  uint4 pa1 = make_uint4(0,0,0,0), pb1 = make_uint4(0,0,0,0); float e1 = 0.f;
  if (s1 >= 0) {
    const u16* row = &hb[(size_t)s1 * 64 + sl * 16];
    pa1 = *reinterpret_cast<const uint4*>(row);
    pb1 = *reinterpret_cast<const uint4*>(row + 8);
    e1 = as_[s1] + adn;
  }
  int i2 = i1 + 16;
  int s2 = (i2 < end) ? csr[i2] : -1;
  while (s0 >= 0) {
    int i3 = i2 + 16;
    int s3 = (i3 < end) ? csr[i3] : -1;
    uint4 pa2 = make_uint4(0,0,0,0), pb2 = make_uint4(0,0,0,0); float e2v = 0.f;
    if (s2 >= 0) {
      const u16* row = &hb[(size_t)s2 * 64 + sl * 16];
      pa2 = *reinterpret_cast<const uint4*>(row);
      pb2 = *reinterpret_cast<const uint4*>(row + 8);
      e2v = as_[s2] + adn;
    }
    float e = (e0 > 0.f) ? e0 : 0.2f * e0;
    float wgt = __expf(e);
    denom += wgt;
    a[0]  += wgt * bflo(pa0.x); a[1]  += wgt * bfhi(pa0.x);
    a[2]  += wgt * bflo(pa0.y); a[3]  += wgt * bfhi(pa0.y);
    a[4]  += wgt * bflo(pa0.z); a[5]  += wgt * bfhi(pa0.z);
    a[6]  += wgt * bflo(pa0.w); a[7]  += wgt * bfhi(pa0.w);
    a[8]  += wgt * bflo(pb0.x); a[9]  += wgt * bfhi(pb0.x);
    a[10] += wgt * bflo(pb0.y); a[11] += wgt * bfhi(pb0.y);
    a[12] += wgt * bflo(pb0.z); a[13] += wgt * bfhi(pb0.z);
    a[14] += wgt * bflo(pb0.w); a[15] += wgt * bfhi(pb0.w);
    s0 = s1; pa0 = pa1; pb0 = pb1; e0 = e1;
    s1 = s2; pa1 = pa2; pb1 = pb2; e1 = e2v;
    s2 = s3; i2 = i3;
  }
#pragma unroll
  for (int w2 = 4; w2 < 64; w2 <<= 1) denom += __shfl_xor(denom, w2, 64);
#pragma unroll
  for (int j = 0; j < 16; ++j) {
    a[j] += __shfl_xor(a[j], 4, 64);
    a[j] += __shfl_xor(a[j], 8, 64);
    a[j] += __shfl_xor(a[j], 16, 64);
    a[j] += __shfl_xor(a[j], 32, 64);
  }
  if (g == 0) {
    float inv = 1.f / (denom + 1e-16f);
    float* op = &out[(size_t)node * 64 + sl * 16];
    const float* bp = &bias[sl * 16];
#pragma unroll
    for (int q = 0; q < 4; ++q) {
      float4 bq = *reinterpret_cast<const float4*>(bp + q * 4);
      float4 o;
      o.x = fmaxf(a[q * 4 + 0] * inv + bq.x, 0.f);
      o.y = fmaxf(a[q * 4 + 1] * inv + bq.y, 0.f);
      o.z = fmaxf(a[q * 4 + 2] * inv + bq.z, 0.f);
      o.w = fmaxf(a[q * 4 + 3] * inv + bq.w, 0.f);
      *reinterpret_cast<float4*>(op + q * 4) = o;
    }
  }
}

// ---- fused edge MLP: 4 edges/wave, 16 lanes/edge, 3-stage pipeline --------

__global__ __launch_bounds__(256) void edge_mlp(
    const int2* __restrict__ eidx, const float* __restrict__ dist,
    const u16* __restrict__ Pb, const float* __restrict__ W3,
    const float* __restrict__ b1, const float* __restrict__ W2,
    const float* __restrict__ b2, float* __restrict__ out, int nE) {
  __shared__ float4 W3s[16][32];  // [k][q]: cols q*4..q*4+3
  int tid = threadIdx.x;
  for (int idx = tid; idx < 16 * 32; idx += 256) {
    int k = idx >> 5, q = idx & 31;
    W3s[k][q] = *reinterpret_cast<const float4*>(&W3[k * 128 + q * 4]);
  }
  __syncthreads();
  int lane = tid & 63, wv = tid >> 6;
  int g = lane >> 4, sl = lane & 15;   // edge slot g, 8 cols per lane
  float4 b1a = *reinterpret_cast<const float4*>(&b1[sl * 8]);
  float4 b1b = *reinterpret_cast<const float4*>(&b1[sl * 8 + 4]);
  float4 w2a = *reinterpret_cast<const float4*>(&W2[sl * 8]);
  float4 w2b = *reinterpret_cast<const float4*>(&W2[sl * 8 + 4]);
  float b2v = b2[0];
  const int stride = gridDim.x * 16;
  // stage0: data resident
  int e0 = (blockIdx.x * 4 + wv) * 4 + g;
  bool v0 = e0 < nE;
  int2 rc0 = v0 ? eidx[e0] : make_int2(0, 0);
  uint4 p1a = make_uint4(0,0,0,0), p2a = make_uint4(0,0,0,0); float dsa = 0.f;
  if (v0) {
    p1a = *reinterpret_cast<const uint4*>(&Pb[(size_t)rc0.x * 256 + sl * 8]);
    p2a = *reinterpret_cast<const uint4*>(&Pb[(size_t)rc0.y * 256 + 128 + sl * 8]);
    dsa = dist[(size_t)e0 * 16 + sl];
  }
  // stage1: data in flight
  int e1 = e0 + stride;
  bool v1 = e1 < nE;
  int2 rc1 = v1 ? eidx[e1] : make_int2(0, 0);
  uint4 p1b = make_uint4(0,0,0,0), p2b = make_uint4(0,0,0,0); float dsb = 0.f;
  if (v1) {
    p1b = *reinterpret_cast<const uint4*>(&Pb[(size_t)rc1.x * 256 + sl * 8]);
    p2b = *reinterpret_cast<const uint4*>(&Pb[(size_t)rc1.y * 256 + 128 + sl * 8]);
    dsb = dist[(size_t)e1 * 16 + sl];
  }
  // stage2: index resident
  int e2 = e1 + stride;
  bool v2 = e2 < nE;
  int2 rc2 = v2 ? eidx[e2] : make_int2(0, 0);
  while (v0) {
    int e3 = e2 + stride;
    bool v3 = e3 < nE;
    int2 rc3 = v3 ? eidx[e3] : make_int2(0, 0);     // index 3 ahead
    uint4 p1c = make_uint4(0,0,0,0), p2c = make_uint4(0,0,0,0); float dsc = 0.f;
    if (v2) {                                        // data 2 ahead
      p1c = *reinterpret_cast<const uint4*>(&Pb[(size_t)rc2.x * 256 + sl * 8]);
      p2c = *reinterpret_cast<const uint4*>(&Pb[(size_t)rc2.y * 256 + 128 + sl * 8]);
      dsc = dist[(size_t)e2 * 16 + sl];
    }
    float a[8];
    a[0] = bflo(p1a.x) + bflo(p2a.x) + b1a.x;
    a[1] = bfhi(p1a.x) + bfhi(p2a.x) + b1a.y;
    a[2] = bflo(p1a.y) + bflo(p2a.y) + b1a.z;
    a[3] = bfhi(p1a.y) + bfhi(p2a.y) + b1a.w;
    a[4] = bflo(p1a.z) + bflo(p2a.z) + b1b.x;
    a[5] = bfhi(p1a.z) + bfhi(p2a.z) + b1b.y;
    a[6] = bflo(p1a.w) + bflo(p2a.w) + b1b.z;
    a[7] = bfhi(p1a.w) + bfhi(p2a.w) + b1b.w;
#pragma unroll
    for (int k = 0; k < 16; ++k) {
      float dk = __shfl(dsa, (g << 4) + k, 64);
      float4 wA = W3s[k][2 * sl];
      float4 wB = W3s[k][2 * sl + 1];
      a[0] += dk * wA.x; a[1] += dk * wA.y; a[2] += dk * wA.z; a[3] += dk * wA.w;
      a[4] += dk * wB.x; a[5] += dk * wB.y; a[6] += dk * wB.z; a[7] += dk * wB.w;
    }
    float p_ = fmaxf(a[0], 0.f) * w2a.x + fmaxf(a[1], 0.f) * w2a.y +
               fmaxf(a[2], 0.f) * w2a.z + fmaxf(a[3], 0.f) * w2a.w +
               fmaxf(a[4], 0.f) * w2b.x + fmaxf(a[5], 0.f) * w2b.y +
               fmaxf(a[6], 0.f) * w2b.z + fmaxf(a[7], 0.f) * w2b.w;
#pragma unroll
    for (int off = 1; off < 16; off <<= 1) p_ += __shfl_xor(p_, off, 16);
    if (sl == 0) out[e0] = 1.f / (1.f + __expf(-(p_ + b2v)));
    // rotate
    e0 = e1; v0 = v1; p1a = p1b; p2a = p2b; dsa = dsb;
    e1 = e2; v1 = v2; p1b = p1c; p2b = p2c; dsb = dsc;
    e2 = e3; v2 = v3; rc2 = rc3;
  }
}

// ---------------- launch ---------------------------------------------------

extern "C" void kernel_launch(void* const* d_in, const int* in_sizes, int n_in,
                              void* d_out, int out_size, void* d_ws, size_t ws_size,
                              hipStream_t stream) {
  const float* x      = (const float*)d_in[0];
  const int*   eidx   = (const int*)d_in[1];
  const float* dist   = (const float*)d_in[2];
  const float* W_g1   = (const float*)d_in[3];
  const float* a1_src = (const float*)d_in[4];
  const float* a1_dst = (const float*)d_in[5];
  const float* b_g1   = (const float*)d_in[6];
  const float* W_g2   = (const float*)d_in[7];
  const float* a2_src = (const float*)d_in[8];
  const float* a2_dst = (const float*)d_in[9];
  const float* b_g2   = (const float*)d_in[10];
  const float* W_m1   = (const float*)d_in[11];
  const float* b_m1   = (const float*)d_in[12];
  const float* W_m2   = (const float*)d_in[13];
  const float* b_m2   = (const float*)d_in[14];
  float* out = (float*)d_out;

  const int n  = in_sizes[0] / GIN;   // 50000
  const int nE = in_sizes[1] / 2;     // 800000
  const int ndir = 2 * nE + n;        // 1,650,000

  char* w = (char*)d_ws;
  size_t off = 0;
  auto alloc = [&](size_t bytes) {
    size_t o = off;
    off += (bytes + 255) & ~(size_t)255;
    return o;
  };
  size_t o_deg    = alloc((size_t)n * 4);
  size_t o_offs   = alloc((size_t)(n + 1) * 4);
  size_t o_cursor = alloc((size_t)n * 4);
  size_t o_as1    = alloc((size_t)n * 4);
  size_t o_ad1    = alloc((size_t)n * 4);
  size_t o_as2    = alloc((size_t)n * 4);
  size_t o_ad2    = alloc((size_t)n * 4);
  size_t o_bsum   = alloc(64 * 4);
  size_t o_bscan  = alloc(64 * 4);
  size_t o_csr    = alloc((size_t)ndir * 4);
  size_t o_big    = alloc((size_t)n * 256 * 2);  // Pb; h1b/h2b overlay
  size_t o_f1     = alloc((size_t)n * GHID * 4);
  size_t o_f2     = alloc((size_t)n * GOUT * 4);
  (void)ws_size;

  int*   deg    = (int*)(w + o_deg);
  int*   offs   = (int*)(w + o_offs);
  int*   cursor = (int*)(w + o_cursor);
  float* as1    = (float*)(w + o_as1);
  float* ad1    = (float*)(w + o_ad1);
  float* as2    = (float*)(w + o_as2);
  float* ad2    = (float*)(w + o_ad2);
  int*   bsum   = (int*)(w + o_bsum);
  int*   bscan  = (int*)(w + o_bscan);
  int*   csr    = (int*)(w + o_csr);
  u16*   h1b    = (u16*)(w + o_big);                          // dead after agg1
  u16*   h2b    = (u16*)(w + o_big + (size_t)n * GHID * 2);   // dead after agg2
  u16*   Pb     = (u16*)(w + o_big);                          // overlays h1b/h2b
  float* f1     = (float*)(w + o_f1);
  float* f2     = (float*)(w + o_f2);

  // 1. XCD-partitioned CSR build + score-accumulator zeroing
  hipMemsetAsync(deg, 0, (size_t)n * 4, stream);
  hipMemsetAsync(as1, 0, (size_t)n * 4, stream);
  hipMemsetAsync(ad1, 0, (size_t)n * 4, stream);
  hipMemsetAsync(as2, 0, (size_t)n * 4, stream);
  hipMemsetAsync(ad2, 0, (size_t)n * 4, stream);
  hist_part<<<2048, 256, 0, stream>>>((const int2*)eidx, deg, nE, n);
  int nb = (n + SCAN_CHUNK - 1) / SCAN_CHUNK;  // 49 (<=64 required)
  scan_partial<<<nb, 256, 0, stream>>>(deg, bsum, n);
  scan_bsums<<<1, 64, 0, stream>>>(bsum, bscan, offs, nb, n);
  scan_final<<<nb, 256, 0, stream>>>(deg, bscan, offs, cursor, n);
  scatter_part<<<2048, 256, 0, stream>>>((const int2*)eidx, offs, cursor, csr, nE, n);

  const int mtiles = (n + 63) / 64;  // 782
  const int BIGK = 1 << 30;

  // 2. h1b = bf16(x @ W_g1), as1/ad1 fused
  gemm_bf<true><<<dim3(mtiles, 2), 256, 0, stream>>>(
      x, x, BIGK, GIN, GIN, W_g1, 0, GHID, h1b, GHID,
      a1_src, a1_dst, as1, ad1, n, GIN);

  // 3. f1 = relu(agg(h1b) + b_g1)
  gat_agg1<<<(n + 3) / 4, 256, 0, stream>>>(h1b, as1, ad1, offs, csr, b_g1, f1, n);

  // 4. h2b = bf16(f1 @ W_g2), as2/ad2 fused
  gemm_bf<true><<<dim3(mtiles, 1), 256, 0, stream>>>(
      f1, f1, BIGK, GHID, GHID, W_g2, 0, GOUT, h2b, GOUT,
      a2_src, a2_dst, as2, ad2, n, GHID);

  // 5. f2 = relu(agg(h2b) + b_g2)
  gat_agg2<<<(n + 3) / 4, 256, 0, stream>>>(h2b, as2, ad2, offs, csr, b_g2, f2, n);

  // 6. Pb = bf16([x|f2] @ W_m1[0:256]) — one dispatch, k-split A, B row-chunk
  gemm_bf<false><<<dim3(mtiles, 4), 256, 0, stream>>>(
      x, f2, GIN, GIN, GOUT, W_m1, 128 * 128, GHID, Pb, 256,
      nullptr, nullptr, nullptr, nullptr, n, GHID);

  // 7. fused edge MLP + sigmoid (original edge order)
  edge_mlp<<<4096, 256, 0, stream>>>((const int2*)eidx, dist, Pb,
                                     W_m1 + 256 * 128, b_m1, W_m2, b_m2, out, nE);
}